// Round 12
// baseline (268.019 us; speedup 1.0000x reference)
//
#include <hip/hip_runtime.h>
#include <hip/hip_bf16.h>
#include <cstdint>
#include <cstddef>

// Problem constants (B=1)
#define EN 400000   // edges
#define NN 25000    // nodes
// D=128, H=4, DK=DV=32

typedef __attribute__((ext_vector_type(8))) short bf16x8;
typedef __attribute__((ext_vector_type(4))) short bf16x4;
typedef __attribute__((ext_vector_type(4))) float f32x4;

__device__ __forceinline__ short f2bf(float f) {
    unsigned int u = __float_as_uint(f);
    u = (u + 0x7fffu + ((u >> 16) & 1u)) >> 16;   // RNE
    return (short)u;
}
__device__ __forceinline__ float bf2f(short s) {
    return __uint_as_float(((unsigned int)(unsigned short)s) << 16);
}

// Identity ds_bpermute: result is DS-defined, so the compiler cannot rematerialize
// it from the original global load -> weight fragments stay register-resident.
__device__ __forceinline__ bf16x8 pin8(bf16x8 v) {
    union { bf16x8 s; int i[4]; } u; u.s = v;
    const int a = (threadIdx.x & 63) << 2;
#pragma unroll
    for (int k = 0; k < 4; ++k) u.i[k] = __builtin_amdgcn_ds_bpermute(a, u.i[k]);
    return u.s;
}

// ---------------- K0: fused weights->bf16 (hi 5 mats, lo 3 mats) + degree histogram ---
__global__ __launch_bounds__(256) void convert_hist_kernel(
    const float* __restrict__ w0, const float* __restrict__ w1,
    const float* __restrict__ w2, const float* __restrict__ w3,
    const float* __restrict__ w4, short* __restrict__ hi, short* __restrict__ lo,
    const int* __restrict__ eidx, int* __restrict__ deg)
{
    if (blockIdx.x < 512) {
        int i = blockIdx.x * 256 + threadIdx.x;      // 131072 threads
        if (i < 81920) {
            int w = i >> 14, off = i & 16383;
            const float* src = (w == 0) ? w0 : (w == 1) ? w1 : (w == 2) ? w2 : (w == 3) ? w3 : w4;
            hi[i] = f2bf(src[off]);
        } else {
            int j = i - 81920;                       // WQ, WK, WE lo parts
            int m = j >> 14, off = j & 16383;
            const float* src = (m == 0) ? w0 : (m == 1) ? w1 : w3;
            float x = src[off];
            short h = f2bf(x);
            lo[j] = f2bf(x - bf2f(h));
        }
    } else {
        int e = (blockIdx.x - 512) * 256 + threadIdx.x;
        if (e < EN) atomicAdd(&deg[eidx[e]], 1);
    }
}

// ---------------- CSR scan ----------------
__global__ __launch_bounds__(1024) void scan_kernel(
    const int* __restrict__ deg, int* __restrict__ base)
{
    __shared__ int part[1024];
    const int t = threadIdx.x;
    const int CH = 25;                       // 1024*25 = 25600 >= NN
    int loc[CH];
    int s = 0;
#pragma unroll
    for (int i = 0; i < CH; ++i) {
        int idx = t * CH + i;
        loc[i] = s;
        s += (idx < NN) ? deg[idx] : 0;
    }
    part[t] = s;
    __syncthreads();
    for (int d = 1; d < 1024; d <<= 1) {
        int v = (t >= d) ? part[t - d] : 0;
        __syncthreads();
        part[t] += v;
        __syncthreads();
    }
    int off = (t > 0) ? part[t - 1] : 0;
#pragma unroll
    for (int i = 0; i < CH; ++i) {
        int idx = t * CH + i;
        if (idx < NN) base[idx] = off + loc[i];
    }
    if (t == 1023) base[NN] = part[1023];
}

// writes pack[e] = {src, tgt, csr_pos, 0} and tgt_csr[csr_pos] = tgt
__global__ __launch_bounds__(256) void scatter_kernel(
    const int* __restrict__ eidx, const int* __restrict__ base,
    int* __restrict__ cnt, int4* __restrict__ pack, int* __restrict__ tgt_csr)
{
    int e = blockIdx.x * 256 + threadIdx.x;
    if (e < EN) {
        int s = eidx[e];
        int tg = eidx[EN + e];
        int p = base[s] + atomicAdd(&cnt[s], 1);
        pack[e] = make_int4(s, tg, p, 0);
        tgt_csr[p] = tg;
    }
}

// ---------------- K1: fused head-split projections (Q,K split-precision; V bf16) ------
// blockIdx.y: 0=Q, 1=K, 2=V. Wave hw = head hw: outdims [32hw, 32hw+32).
__global__ __launch_bounds__(256, 4) void proj_all_kernel(
    const float* __restrict__ inQ, const float* __restrict__ inK,
    const float* __restrict__ inV,
    const short* __restrict__ WhiBase, const short* __restrict__ WloBase,
    float* __restrict__ Qf, float* __restrict__ Kf, short* __restrict__ Vb)
{
    const int mode = blockIdx.y;
    const int lane = threadIdx.x & 63;
    const int hw = threadIdx.x >> 6;          // head / wave
    const int el = lane & 15;
    const int g  = lane >> 4;
    const int ntiles = (NN + 15) >> 4;

    if (mode < 2) {
        const float* X = mode ? inK : inQ;
        const short* Whi = WhiBase + mode * 16384;
        const short* Wlo = WloBase + mode * 16384;
        float* P = mode ? Kf : Qf;

        bf16x8 wh[2][4], wl[2][4];
#pragma unroll
        for (int dtt = 0; dtt < 2; ++dtt)
#pragma unroll
            for (int kc = 0; kc < 4; ++kc) {
                const int r = hw * 32 + dtt * 16 + el;
                const int c = kc * 32 + g * 8;
                wh[dtt][kc] = pin8(*(const bf16x8*)(Whi + r * 128 + c));
                wl[dtt][kc] = pin8(*(const bf16x8*)(Wlo + r * 128 + c));
            }

        for (int tile = blockIdx.x; tile < ntiles; tile += gridDim.x) {
            const int row = tile * 16 + el;
            const int rc = row < NN ? row : NN - 1;
            const float* xrow = X + (size_t)rc * 128;
            f32x4 acc0 = {}, acc1 = {};
#pragma unroll
            for (int kc = 0; kc < 4; ++kc) {
                const int kb = kc * 32 + g * 8;
                f32x4 x0 = *(const f32x4*)(xrow + kb);
                f32x4 x1 = *(const f32x4*)(xrow + kb + 4);
                bf16x8 bh, bl;
#pragma unroll
                for (int j = 0; j < 4; ++j) {
                    bh[j] = f2bf(x0[j]); bl[j] = f2bf(x0[j] - bf2f(bh[j]));
                    bh[4 + j] = f2bf(x1[j]); bl[4 + j] = f2bf(x1[j] - bf2f(bh[4 + j]));
                }
                acc0 = __builtin_amdgcn_mfma_f32_16x16x32_bf16(wh[0][kc], bh, acc0, 0, 0, 0);
                acc0 = __builtin_amdgcn_mfma_f32_16x16x32_bf16(wh[0][kc], bl, acc0, 0, 0, 0);
                acc0 = __builtin_amdgcn_mfma_f32_16x16x32_bf16(wl[0][kc], bh, acc0, 0, 0, 0);
                acc1 = __builtin_amdgcn_mfma_f32_16x16x32_bf16(wh[1][kc], bh, acc1, 0, 0, 0);
                acc1 = __builtin_amdgcn_mfma_f32_16x16x32_bf16(wh[1][kc], bl, acc1, 0, 0, 0);
                acc1 = __builtin_amdgcn_mfma_f32_16x16x32_bf16(wl[1][kc], bh, acc1, 0, 0, 0);
            }
            if (row < NN) {
                *(f32x4*)(P + (size_t)row * 128 + hw * 32 + g * 4)      = acc0;
                *(f32x4*)(P + (size_t)row * 128 + hw * 32 + 16 + g * 4) = acc1;
            }
        }
    } else {
        const short* Wb = WhiBase + 2 * 16384;
        bf16x8 wv[2][4];
#pragma unroll
        for (int dtt = 0; dtt < 2; ++dtt)
#pragma unroll
            for (int kc = 0; kc < 4; ++kc)
                wv[dtt][kc] = pin8(*(const bf16x8*)(Wb + (hw * 32 + dtt * 16 + el) * 128 + kc * 32 + g * 8));

        for (int tile = blockIdx.x; tile < ntiles; tile += gridDim.x) {
            const int row = tile * 16 + el;
            const int rc = row < NN ? row : NN - 1;
            const float* xrow = inV + (size_t)rc * 128;
            f32x4 acc0 = {}, acc1 = {};
#pragma unroll
            for (int kc = 0; kc < 4; ++kc) {
                const int kb = kc * 32 + g * 8;
                f32x4 x0 = *(const f32x4*)(xrow + kb);
                f32x4 x1 = *(const f32x4*)(xrow + kb + 4);
                bf16x8 b;
#pragma unroll
                for (int j = 0; j < 4; ++j) { b[j] = f2bf(x0[j]); b[4 + j] = f2bf(x1[j]); }
                acc0 = __builtin_amdgcn_mfma_f32_16x16x32_bf16(wv[0][kc], b, acc0, 0, 0, 0);
                acc1 = __builtin_amdgcn_mfma_f32_16x16x32_bf16(wv[1][kc], b, acc1, 0, 0, 0);
            }
            if (row < NN) {
                bf16x4 o0, o1;
#pragma unroll
                for (int j = 0; j < 4; ++j) { o0[j] = f2bf(acc0[j]); o1[j] = f2bf(acc1[j]); }
                *(bf16x4*)(Vb + (size_t)row * 128 + hw * 32 + g * 4)      = o0;
                *(bf16x4*)(Vb + (size_t)row * 128 + hw * 32 + 16 + g * 4) = o1;
            }
        }
    }
}

// ---------------- K2a: 32-edge LDS-staged Ef-GEMM + score + exp ----------------
// 2x wider tile than R8-R11: one barrier + one efeat-latency stall per 32 edges
// instead of 16 — per-edge fixed cost halves; MFMA phase (48 MFMAs) gives gathers
// more in-iteration slack. Same counted-vmcnt barrier (lgkmcnt only). Weights
// pinned via pin8 (AGPR side). bounds(256,3): ~170-reg budget, no spill.
__global__ __launch_bounds__(256, 3) void edge_score_kernel(
    const int4* __restrict__ pack, const float* __restrict__ efeat,
    const float* __restrict__ Qf, const float* __restrict__ Kf,
    const short* __restrict__ WEhi, const short* __restrict__ WElo,
    float* __restrict__ attn_out, float* __restrict__ attn_csr)
{
    __shared__ short lds_hi[2][32][136];   // [buf][edge][dim]
    __shared__ short lds_lo[2][32][136];

    const int t    = threadIdx.x;
    const int lane = t & 63;
    const int hw   = t >> 6;              // head / wave
    const int el   = lane & 15;
    const int g    = lane >> 4;
    const int se   = t >> 3;              // staging: edge 0..31
    const int sd   = (t & 7) * 16;        // staging: dim (16 floats per thread)
    const int NT   = EN / 32;             // 12500

    // pinned weight fragments
    bf16x8 wh[2][4], wl[2][4];
#pragma unroll
    for (int dtt = 0; dtt < 2; ++dtt)
#pragma unroll
        for (int kc = 0; kc < 4; ++kc) {
            const int r = hw * 32 + dtt * 16 + el;
            const int c = kc * 32 + g * 8;
            wh[dtt][kc] = pin8(*(const bf16x8*)(WEhi + r * 128 + c));
            wl[dtt][kc] = pin8(*(const bf16x8*)(WElo + r * 128 + c));
        }

    const int dbase = hw * 32 + g * 4;
    int tile = blockIdx.x;
    int4 pkA = pack[(size_t)tile * 32 + el];
    int4 pkB = pack[(size_t)tile * 32 + 16 + el];

    // prologue: stage tile0 -> LDS[0]
    {
        const float* p = efeat + ((size_t)tile * 32 + se) * 128 + sd;
        f32x4 a = *(const f32x4*)p;
        f32x4 b = *(const f32x4*)(p + 4);
        f32x4 c = *(const f32x4*)(p + 8);
        f32x4 d = *(const f32x4*)(p + 12);
        bf16x8 h0, l0, h1, l1;
#pragma unroll
        for (int j = 0; j < 4; ++j) {
            h0[j] = f2bf(a[j]);     l0[j] = f2bf(a[j] - bf2f(h0[j]));
            h0[4 + j] = f2bf(b[j]); l0[4 + j] = f2bf(b[j] - bf2f(h0[4 + j]));
            h1[j] = f2bf(c[j]);     l1[j] = f2bf(c[j] - bf2f(h1[j]));
            h1[4 + j] = f2bf(d[j]); l1[4 + j] = f2bf(d[j] - bf2f(h1[4 + j]));
        }
        *(bf16x8*)&lds_hi[0][se][sd]     = h0;
        *(bf16x8*)&lds_hi[0][se][sd + 8] = h1;
        *(bf16x8*)&lds_lo[0][se][sd]     = l0;
        *(bf16x8*)&lds_lo[0][se][sd + 8] = l1;
    }

    int buf = 0;
    while (true) {
        // A) gathers for current tile (both edge halves; consumed at E after MFMA)
        const float* qrA = Qf + (size_t)pkA.x * 128 + dbase;
        const float* krA = Kf + (size_t)pkA.y * 128 + dbase;
        const float* qrB = Qf + (size_t)pkB.x * 128 + dbase;
        const float* krB = Kf + (size_t)pkB.y * 128 + dbase;
        f32x4 qa0 = *(const f32x4*)(qrA);
        f32x4 qa1 = *(const f32x4*)(qrA + 16);
        f32x4 ka0 = *(const f32x4*)(krA);
        f32x4 ka1 = *(const f32x4*)(krA + 16);
        f32x4 qb0 = *(const f32x4*)(qrB);
        f32x4 qb1 = *(const f32x4*)(qrB + 16);
        f32x4 kb0 = *(const f32x4*)(krB);
        f32x4 kb1 = *(const f32x4*)(krB + 16);

        // B) staging loads for next tile + pack prefetch
        const int next = tile + (int)gridDim.x;
        const bool has_next = next < NT;
        const int tload = has_next ? next : tile;
        const float* np = efeat + ((size_t)tload * 32 + se) * 128 + sd;
        f32x4 ea = *(const f32x4*)np;
        f32x4 eb = *(const f32x4*)(np + 4);
        f32x4 ec = *(const f32x4*)(np + 8);
        f32x4 ed = *(const f32x4*)(np + 12);
        int4 pkA2 = pack[(size_t)tload * 32 + el];
        int4 pkB2 = pack[(size_t)tload * 32 + 16 + el];

        // C) barrier: order LDS double-buffer only — do NOT drain vmcnt
        asm volatile("s_waitcnt lgkmcnt(0)" ::: "memory");
        __builtin_amdgcn_s_barrier();
        __builtin_amdgcn_sched_barrier(0);

        // D) MFMA phase: two 16-edge sub-tiles from LDS (lgkmcnt only)
        __builtin_amdgcn_s_setprio(1);
        f32x4 aA0 = {}, aA1 = {}, aB0 = {}, aB1 = {};
#pragma unroll
        for (int kc = 0; kc < 4; ++kc) {
            const int kb = kc * 32 + g * 8;
            bf16x8 bhA = *(const bf16x8*)&lds_hi[buf][el][kb];
            bf16x8 blA = *(const bf16x8*)&lds_lo[buf][el][kb];
            bf16x8 bhB = *(const bf16x8*)&lds_hi[buf][16 + el][kb];
            bf16x8 blB = *(const bf16x8*)&lds_lo[buf][16 + el][kb];
            aA0 = __builtin_amdgcn_mfma_f32_16x16x32_bf16(wh[0][kc], bhA, aA0, 0, 0, 0);
            aA0 = __builtin_amdgcn_mfma_f32_16x16x32_bf16(wh[0][kc], blA, aA0, 0, 0, 0);
            aA0 = __builtin_amdgcn_mfma_f32_16x16x32_bf16(wl[0][kc], bhA, aA0, 0, 0, 0);
            aA1 = __builtin_amdgcn_mfma_f32_16x16x32_bf16(wh[1][kc], bhA, aA1, 0, 0, 0);
            aA1 = __builtin_amdgcn_mfma_f32_16x16x32_bf16(wh[1][kc], blA, aA1, 0, 0, 0);
            aA1 = __builtin_amdgcn_mfma_f32_16x16x32_bf16(wl[1][kc], bhA, aA1, 0, 0, 0);
            aB0 = __builtin_amdgcn_mfma_f32_16x16x32_bf16(wh[0][kc], bhB, aB0, 0, 0, 0);
            aB0 = __builtin_amdgcn_mfma_f32_16x16x32_bf16(wh[0][kc], blB, aB0, 0, 0, 0);
            aB0 = __builtin_amdgcn_mfma_f32_16x16x32_bf16(wl[0][kc], bhB, aB0, 0, 0, 0);
            aB1 = __builtin_amdgcn_mfma_f32_16x16x32_bf16(wh[1][kc], bhB, aB1, 0, 0, 0);
            aB1 = __builtin_amdgcn_mfma_f32_16x16x32_bf16(wh[1][kc], blB, aB1, 0, 0, 0);
            aB1 = __builtin_amdgcn_mfma_f32_16x16x32_bf16(wl[1][kc], bhB, aB1, 0, 0, 0);
        }
        __builtin_amdgcn_s_setprio(0);

        // E) combine both edges (gathers have had the whole MFMA phase to land)
        float pA = 0.f, pB = 0.f;
#pragma unroll
        for (int j = 0; j < 4; ++j) {
            pA += qa0[j] * ka0[j] * aA0[j];
            pA += qa1[j] * ka1[j] * aA1[j];
            pB += qb0[j] * kb0[j] * aB0[j];
            pB += qb1[j] * kb1[j] * aB1[j];
        }
        pA += __shfl_xor(pA, 16, 64);
        pA += __shfl_xor(pA, 32, 64);
        pB += __shfl_xor(pB, 16, 64);
        pB += __shfl_xor(pB, 32, 64);
        float sA = fminf(5.0f, fmaxf(-5.0f, pA * 0.17677669529663687f));
        float sB = fminf(5.0f, fmaxf(-5.0f, pB * 0.17677669529663687f));
        const float aAv = __expf(sA);
        const float aBv = __expf(sB);

        const int ebase = tile * 32 + el;
        if (g == 0) {
            attn_out[(size_t)hw * EN + ebase]      = aAv;   // 128B contiguous per wave
            attn_out[(size_t)hw * EN + ebase + 16] = aBv;
            attn_csr[(size_t)pkA.z * 4 + hw] = aAv;         // scattered 4B
            attn_csr[(size_t)pkB.z * 4 + hw] = aBv;
        }

        if (!has_next) break;

        // H) convert + write next tile into LDS[buf^1]
        {
            bf16x8 h0, l0, h1, l1;
#pragma unroll
            for (int j = 0; j < 4; ++j) {
                h0[j] = f2bf(ea[j]);     l0[j] = f2bf(ea[j] - bf2f(h0[j]));
                h0[4 + j] = f2bf(eb[j]); l0[4 + j] = f2bf(eb[j] - bf2f(h0[4 + j]));
                h1[j] = f2bf(ec[j]);     l1[j] = f2bf(ec[j] - bf2f(h1[j]));
                h1[4 + j] = f2bf(ed[j]); l1[4 + j] = f2bf(ed[j] - bf2f(h1[4 + j]));
            }
            *(bf16x8*)&lds_hi[buf ^ 1][se][sd]     = h0;
            *(bf16x8*)&lds_hi[buf ^ 1][se][sd + 8] = h1;
            *(bf16x8*)&lds_lo[buf ^ 1][se][sd]     = l0;
            *(bf16x8*)&lds_lo[buf ^ 1][se][sd + 8] = l1;
        }
        tile = next;
        pkA = pkA2;
        pkB = pkB2;
        buf ^= 1;
    }
}

// ---------------- K2b: per-node gather-reduce + W_fc matvec + residual + LN ----------
// 512 threads = 32 nodes/block: one W_fc LDS copy amortized 2x.
__global__ __launch_bounds__(512) void node_kernel(
    const int* __restrict__ base, const int* __restrict__ tgt_csr,
    const float* __restrict__ attn_csr, const short* __restrict__ Vb,
    const short* __restrict__ Wfcb, const float* __restrict__ inQ,
    const float* __restrict__ gamma, const float* __restrict__ beta,
    float* __restrict__ y)
{
    __shared__ short wlds[128 * 136];   // padded: stride 136 bf16
    __shared__ float alds[32 * 132];    // padded: stride 132 f32

    const int t = threadIdx.x;
    // stage W_fc: thread handles row r=t>>2, cols (t&3)*32..+31
    {
        const int r = t >> 2, colb = (t & 3) * 32;
#pragma unroll
        for (int c = 0; c < 4; ++c) {
            bf16x8 w = *(const bf16x8*)(Wfcb + r * 128 + colb + c * 8);
            *(bf16x8*)(&wlds[r * 136 + colb + c * 8]) = w;
        }
    }

    const int n_l = t >> 4;             // 0..31
    const int el  = t & 15;
    const int node = blockIdx.x * 32 + n_l;

    int b0 = 0, b1 = 0;
    if (node < NN) { b0 = base[node]; b1 = base[node + 1]; }
    float acc[8] = {};
    float csum = 0.f;
    const int h = el >> 2;

    int p = b0;
    for (; p + 8 <= b1; p += 8) {      // unroll x8 for memory-level parallelism
        int   tg[8];
        float aa[8];
        bf16x8 vv[8];
#pragma unroll
        for (int u = 0; u < 8; ++u) tg[u] = tgt_csr[p + u];
#pragma unroll
        for (int u = 0; u < 8; ++u) aa[u] = attn_csr[(size_t)(p + u) * 4 + h];
#pragma unroll
        for (int u = 0; u < 8; ++u) vv[u] = *(const bf16x8*)(Vb + (size_t)tg[u] * 128 + el * 8);
#pragma unroll
        for (int u = 0; u < 8; ++u) {
            csum += aa[u];
#pragma unroll
            for (int j = 0; j < 8; ++j) acc[j] += aa[u] * bf2f(vv[u][j]);
        }
    }
    for (; p < b1; ++p) {
        const int tg = tgt_csr[p];
        const float a = attn_csr[(size_t)p * 4 + h];
        bf16x8 v = *(const bf16x8*)(Vb + (size_t)tg * 128 + el * 8);
        csum += a;
#pragma unroll
        for (int j = 0; j < 8; ++j) acc[j] += a * bf2f(v[j]);
    }

    const float invc = 1.0f / (csum + 1e-8f);
#pragma unroll
    for (int j = 0; j < 8; ++j) alds[n_l * 132 + el * 8 + j] = acc[j] * invc;
    __syncthreads();

    float fc[8] = {};
#pragma unroll 4
    for (int k0 = 0; k0 < 128; k0 += 8) {
        float a8[8];
#pragma unroll
        for (int j = 0; j < 8; ++j) a8[j] = alds[n_l * 132 + k0 + j];
#pragma unroll
        for (int i = 0; i < 8; ++i) {
            const int d = el + 16 * i;
            bf16x8 w = *(const bf16x8*)(&wlds[d * 136 + k0]);
#pragma unroll
            for (int j = 0; j < 8; ++j) fc[i] += a8[j] * bf2f(w[j]);
        }
    }

    if (node < NN) {
        float x[8];
        float s = 0.f, s2 = 0.f;
#pragma unroll
        for (int i = 0; i < 8; ++i) {
            const int d = el + 16 * i;
            x[i] = fc[i] + inQ[(size_t)node * 128 + d];
            s += x[i]; s2 += x[i] * x[i];
        }
        s  += __shfl_xor(s, 1, 64);  s2 += __shfl_xor(s2, 1, 64);
        s  += __shfl_xor(s, 2, 64);  s2 += __shfl_xor(s2, 2, 64);
        s  += __shfl_xor(s, 4, 64);  s2 += __shfl_xor(s2, 4, 64);
        s  += __shfl_xor(s, 8, 64);  s2 += __shfl_xor(s2, 8, 64);
        const float mu = s * (1.0f / 128.0f);
        const float var = s2 * (1.0f / 128.0f) - mu * mu;
        const float rstd = rsqrtf(var + 1e-5f);
#pragma unroll
        for (int i = 0; i < 8; ++i) {
            const int d = el + 16 * i;
            y[(size_t)node * 128 + d] = (x[i] - mu) * rstd * gamma[d] + beta[d];
        }
    }
}

// ---------------- launcher ----------------
extern "C" void kernel_launch(void* const* d_in, const int* in_sizes, int n_in,
                              void* d_out, int out_size, void* d_ws, size_t ws_size,
                              hipStream_t stream) {
    const int*   eidx  = (const int*)d_in[0];
    const float* efeat = (const float*)d_in[1];
    const float* inQ   = (const float*)d_in[2];
    const float* inK   = (const float*)d_in[3];
    const float* inV   = (const float*)d_in[4];
    const float* WQ    = (const float*)d_in[5];
    const float* WK    = (const float*)d_in[6];
    const float* WV    = (const float*)d_in[7];
    const float* WE    = (const float*)d_in[8];
    const float* Wfc   = (const float*)d_in[9];
    const float* gamma = (const float*)d_in[10];
    const float* beta  = (const float*)d_in[11];

    float* y = (float*)d_out;
    float* attn_out = y + (size_t)NN * 128;   // 3,200,000

    // ws layout (bytes): same as R6-R11
    char* ws = (char*)d_ws;
    float* Qf      = (float*)ws;
    float* Kf      = (float*)(ws + 12800000);
    short* Vb      = (short*)(ws + 25600000);
    short* Whi     = (short*)(ws + 32000000);
    short* Wlo     = (short*)(ws + 32163840);
    float* attn_csr= (float*)(ws + 32262144);
    int*   tgt_csr = (int*)  (ws + 38662144);
    int4*  pack    = (int4*) (ws + 40262144);
    int*   deg     = (int*)  (ws + 46662144);
    int*   cnt     = (int*)  (ws + 46762496);
    int*   base    = (int*)  (ws + 46862848);

    hipMemsetAsync(deg, 0, 200704, stream);   // deg + cnt

    convert_hist_kernel<<<512 + (EN + 255) / 256, 256, 0, stream>>>(
        WQ, WK, WV, WE, Wfc, Whi, Wlo, eidx, deg);
    scan_kernel<<<1, 1024, 0, stream>>>(deg, base);
    scatter_kernel<<<(EN + 255) / 256, 256, 0, stream>>>(eidx, base, cnt, pack, tgt_csr);

    dim3 pg(391, 3);
    proj_all_kernel<<<pg, 256, 0, stream>>>(inQ, inK, inV, Whi, Wlo, Qf, Kf, Vb);

    edge_score_kernel<<<1024, 256, 0, stream>>>(pack, efeat, Qf, Kf,
                                                Whi + 3 * 16384, Wlo + 2 * 16384,
                                                attn_out, attn_csr);

    node_kernel<<<(NN + 31) / 32, 512, 0, stream>>>(base, tgt_csr, attn_csr, Vb,
                                                    Whi + 4 * 16384, inQ, gamma, beta, y);
}

// Round 13
// 255.732 us; speedup vs baseline: 1.0480x; 1.0480x over previous
//
#include <hip/hip_runtime.h>
#include <hip/hip_bf16.h>
#include <cstdint>
#include <cstddef>

// Problem constants (B=1)
#define EN 400000   // edges
#define NN 25000    // nodes
// D=128, H=4, DK=DV=32

typedef __attribute__((ext_vector_type(8))) short bf16x8;
typedef __attribute__((ext_vector_type(4))) short bf16x4;
typedef __attribute__((ext_vector_type(4))) float f32x4;

__device__ __forceinline__ short f2bf(float f) {
    unsigned int u = __float_as_uint(f);
    u = (u + 0x7fffu + ((u >> 16) & 1u)) >> 16;   // RNE
    return (short)u;
}
__device__ __forceinline__ float bf2f(short s) {
    return __uint_as_float(((unsigned int)(unsigned short)s) << 16);
}

// Identity ds_bpermute: result is DS-defined, so the compiler cannot rematerialize
// it from the original global load -> weight fragments stay register-resident.
__device__ __forceinline__ bf16x8 pin8(bf16x8 v) {
    union { bf16x8 s; int i[4]; } u; u.s = v;
    const int a = (threadIdx.x & 63) << 2;
#pragma unroll
    for (int k = 0; k < 4; ++k) u.i[k] = __builtin_amdgcn_ds_bpermute(a, u.i[k]);
    return u.s;
}

// ---------------- K0: fused weights->bf16 (hi 5 mats, lo 3 mats) + degree histogram ---
__global__ __launch_bounds__(256) void convert_hist_kernel(
    const float* __restrict__ w0, const float* __restrict__ w1,
    const float* __restrict__ w2, const float* __restrict__ w3,
    const float* __restrict__ w4, short* __restrict__ hi, short* __restrict__ lo,
    const int* __restrict__ eidx, int* __restrict__ deg)
{
    if (blockIdx.x < 512) {
        int i = blockIdx.x * 256 + threadIdx.x;      // 131072 threads
        if (i < 81920) {
            int w = i >> 14, off = i & 16383;
            const float* src = (w == 0) ? w0 : (w == 1) ? w1 : (w == 2) ? w2 : (w == 3) ? w3 : w4;
            hi[i] = f2bf(src[off]);
        } else {
            int j = i - 81920;                       // WQ, WK, WE lo parts
            int m = j >> 14, off = j & 16383;
            const float* src = (m == 0) ? w0 : (m == 1) ? w1 : w3;
            float x = src[off];
            short h = f2bf(x);
            lo[j] = f2bf(x - bf2f(h));
        }
    } else {
        int e = (blockIdx.x - 512) * 256 + threadIdx.x;
        if (e < EN) atomicAdd(&deg[eidx[e]], 1);
    }
}

// ---------------- CSR scan ----------------
__global__ __launch_bounds__(1024) void scan_kernel(
    const int* __restrict__ deg, int* __restrict__ base)
{
    __shared__ int part[1024];
    const int t = threadIdx.x;
    const int CH = 25;                       // 1024*25 = 25600 >= NN
    int loc[CH];
    int s = 0;
#pragma unroll
    for (int i = 0; i < CH; ++i) {
        int idx = t * CH + i;
        loc[i] = s;
        s += (idx < NN) ? deg[idx] : 0;
    }
    part[t] = s;
    __syncthreads();
    for (int d = 1; d < 1024; d <<= 1) {
        int v = (t >= d) ? part[t - d] : 0;
        __syncthreads();
        part[t] += v;
        __syncthreads();
    }
    int off = (t > 0) ? part[t - 1] : 0;
#pragma unroll
    for (int i = 0; i < CH; ++i) {
        int idx = t * CH + i;
        if (idx < NN) base[idx] = off + loc[i];
    }
    if (t == 1023) base[NN] = part[1023];
}

// writes pack[e] = {src, tgt, csr_pos, 0} and tgt_csr[csr_pos] = tgt
__global__ __launch_bounds__(256) void scatter_kernel(
    const int* __restrict__ eidx, const int* __restrict__ base,
    int* __restrict__ cnt, int4* __restrict__ pack, int* __restrict__ tgt_csr)
{
    int e = blockIdx.x * 256 + threadIdx.x;
    if (e < EN) {
        int s = eidx[e];
        int tg = eidx[EN + e];
        int p = base[s] + atomicAdd(&cnt[s], 1);
        pack[e] = make_int4(s, tg, p, 0);
        tgt_csr[p] = tg;
    }
}

// ---------------- K1: fused head-split projections (Q,K split-precision; V bf16) ------
// blockIdx.y: 0=Q, 1=K, 2=V. Wave hw = head hw: outdims [32hw, 32hw+32).
__global__ __launch_bounds__(256, 4) void proj_all_kernel(
    const float* __restrict__ inQ, const float* __restrict__ inK,
    const float* __restrict__ inV,
    const short* __restrict__ WhiBase, const short* __restrict__ WloBase,
    float* __restrict__ Qf, float* __restrict__ Kf, short* __restrict__ Vb)
{
    const int mode = blockIdx.y;
    const int lane = threadIdx.x & 63;
    const int hw = threadIdx.x >> 6;          // head / wave
    const int el = lane & 15;
    const int g  = lane >> 4;
    const int ntiles = (NN + 15) >> 4;

    if (mode < 2) {
        const float* X = mode ? inK : inQ;
        const short* Whi = WhiBase + mode * 16384;
        const short* Wlo = WloBase + mode * 16384;
        float* P = mode ? Kf : Qf;

        bf16x8 wh[2][4], wl[2][4];
#pragma unroll
        for (int dtt = 0; dtt < 2; ++dtt)
#pragma unroll
            for (int kc = 0; kc < 4; ++kc) {
                const int r = hw * 32 + dtt * 16 + el;
                const int c = kc * 32 + g * 8;
                wh[dtt][kc] = pin8(*(const bf16x8*)(Whi + r * 128 + c));
                wl[dtt][kc] = pin8(*(const bf16x8*)(Wlo + r * 128 + c));
            }

        for (int tile = blockIdx.x; tile < ntiles; tile += gridDim.x) {
            const int row = tile * 16 + el;
            const int rc = row < NN ? row : NN - 1;
            const float* xrow = X + (size_t)rc * 128;
            f32x4 acc0 = {}, acc1 = {};
#pragma unroll
            for (int kc = 0; kc < 4; ++kc) {
                const int kb = kc * 32 + g * 8;
                f32x4 x0 = *(const f32x4*)(xrow + kb);
                f32x4 x1 = *(const f32x4*)(xrow + kb + 4);
                bf16x8 bh, bl;
#pragma unroll
                for (int j = 0; j < 4; ++j) {
                    bh[j] = f2bf(x0[j]); bl[j] = f2bf(x0[j] - bf2f(bh[j]));
                    bh[4 + j] = f2bf(x1[j]); bl[4 + j] = f2bf(x1[j] - bf2f(bh[4 + j]));
                }
                acc0 = __builtin_amdgcn_mfma_f32_16x16x32_bf16(wh[0][kc], bh, acc0, 0, 0, 0);
                acc0 = __builtin_amdgcn_mfma_f32_16x16x32_bf16(wh[0][kc], bl, acc0, 0, 0, 0);
                acc0 = __builtin_amdgcn_mfma_f32_16x16x32_bf16(wl[0][kc], bh, acc0, 0, 0, 0);
                acc1 = __builtin_amdgcn_mfma_f32_16x16x32_bf16(wh[1][kc], bh, acc1, 0, 0, 0);
                acc1 = __builtin_amdgcn_mfma_f32_16x16x32_bf16(wh[1][kc], bl, acc1, 0, 0, 0);
                acc1 = __builtin_amdgcn_mfma_f32_16x16x32_bf16(wl[1][kc], bh, acc1, 0, 0, 0);
            }
            if (row < NN) {
                *(f32x4*)(P + (size_t)row * 128 + hw * 32 + g * 4)      = acc0;
                *(f32x4*)(P + (size_t)row * 128 + hw * 32 + 16 + g * 4) = acc1;
            }
        }
    } else {
        const short* Wb = WhiBase + 2 * 16384;
        bf16x8 wv[2][4];
#pragma unroll
        for (int dtt = 0; dtt < 2; ++dtt)
#pragma unroll
            for (int kc = 0; kc < 4; ++kc)
                wv[dtt][kc] = pin8(*(const bf16x8*)(Wb + (hw * 32 + dtt * 16 + el) * 128 + kc * 32 + g * 8));

        for (int tile = blockIdx.x; tile < ntiles; tile += gridDim.x) {
            const int row = tile * 16 + el;
            const int rc = row < NN ? row : NN - 1;
            const float* xrow = inV + (size_t)rc * 128;
            f32x4 acc0 = {}, acc1 = {};
#pragma unroll
            for (int kc = 0; kc < 4; ++kc) {
                const int kb = kc * 32 + g * 8;
                f32x4 x0 = *(const f32x4*)(xrow + kb);
                f32x4 x1 = *(const f32x4*)(xrow + kb + 4);
                bf16x8 b;
#pragma unroll
                for (int j = 0; j < 4; ++j) { b[j] = f2bf(x0[j]); b[4 + j] = f2bf(x1[j]); }
                acc0 = __builtin_amdgcn_mfma_f32_16x16x32_bf16(wv[0][kc], b, acc0, 0, 0, 0);
                acc1 = __builtin_amdgcn_mfma_f32_16x16x32_bf16(wv[1][kc], b, acc1, 0, 0, 0);
            }
            if (row < NN) {
                bf16x4 o0, o1;
#pragma unroll
                for (int j = 0; j < 4; ++j) { o0[j] = f2bf(acc0[j]); o1[j] = f2bf(acc1[j]); }
                *(bf16x4*)(Vb + (size_t)row * 128 + hw * 32 + g * 4)      = o0;
                *(bf16x4*)(Vb + (size_t)row * 128 + hw * 32 + 16 + g * 4) = o1;
            }
        }
    }
}

// ---------------- K2a: LDS-staged Ef-GEMM + score + exp (write-late staging) ----------
// T14 schedule: phase B issues efeat loads for tile i+2; phase H writes tile i+1 to
// LDS from registers loaded ONE FULL ITERATION earlier (~1000cy slack >= 900cy HBM
// latency) — the H-phase staging stall is gone. Gathers stay same-iteration (E-stall
// ~300cy, partially covered by MFMA). Counted-vmcnt barrier (lgkmcnt only). Weights
// pinned via pin8. bounds(256,3): ~170-reg budget for ~96-112 arch + 64 AGPR.
__global__ __launch_bounds__(256, 3) void edge_score_kernel(
    const int4* __restrict__ pack, const float* __restrict__ efeat,
    const float* __restrict__ Qf, const float* __restrict__ Kf,
    const short* __restrict__ WEhi, const short* __restrict__ WElo,
    float* __restrict__ attn_out, float* __restrict__ attn_csr)
{
    __shared__ short lds_hi[2][16][136];   // [buf][edge][dim]
    __shared__ short lds_lo[2][16][136];

    const int t    = threadIdx.x;
    const int lane = t & 63;
    const int hw   = t >> 6;              // head / wave
    const int el   = lane & 15;
    const int g    = lane >> 4;
    const int se   = t >> 4;              // staging: edge 0..15
    const int sd   = (t & 15) * 8;        // staging: dim
    const int NT   = EN / 16;

    // pinned weight fragments
    bf16x8 wh[2][4], wl[2][4];
#pragma unroll
    for (int dtt = 0; dtt < 2; ++dtt)
#pragma unroll
        for (int kc = 0; kc < 4; ++kc) {
            const int r = hw * 32 + dtt * 16 + el;
            const int c = kc * 32 + g * 8;
            wh[dtt][kc] = pin8(*(const bf16x8*)(WEhi + r * 128 + c));
            wl[dtt][kc] = pin8(*(const bf16x8*)(WElo + r * 128 + c));
        }

    const int dbase = hw * 32 + g * 4;
    int tile = blockIdx.x;
    int4 pk = pack[tile * 16 + el];

    // prologue: synchronous stage tile0 -> LDS[0]
    {
        const float* p = efeat + ((size_t)tile * 16 + se) * 128 + sd;
        f32x4 a = *(const f32x4*)p;
        f32x4 b = *(const f32x4*)(p + 4);
        bf16x8 h8, l8;
#pragma unroll
        for (int j = 0; j < 4; ++j) {
            h8[j] = f2bf(a[j]);     l8[j] = f2bf(a[j] - bf2f(h8[j]));
            h8[4 + j] = f2bf(b[j]); l8[4 + j] = f2bf(b[j] - bf2f(h8[4 + j]));
        }
        *(bf16x8*)&lds_hi[0][se][sd] = h8;
        *(bf16x8*)&lds_lo[0][se][sd] = l8;
    }
    // preload tile1 data into registers (written to LDS at end of iteration 0)
    f32x4 eA, eB;
    int4 pk1;
    {
        const int t1 = tile + (int)gridDim.x;
        const int tl1 = (t1 < NT) ? t1 : tile;
        const float* np = efeat + ((size_t)tl1 * 16 + se) * 128 + sd;
        eA = *(const f32x4*)np;
        eB = *(const f32x4*)(np + 4);
        pk1 = pack[tl1 * 16 + el];
    }

    int buf = 0;
    while (true) {
        // A) gathers for CURRENT tile (consumed at E, after the MFMA phase)
        const float* qrow = Qf + (size_t)pk.x * 128 + dbase;
        const float* krow = Kf + (size_t)pk.y * 128 + dbase;
        f32x4 q0 = *(const f32x4*)(qrow);
        f32x4 q1 = *(const f32x4*)(qrow + 16);
        f32x4 k0 = *(const f32x4*)(krow);
        f32x4 k1 = *(const f32x4*)(krow + 16);

        // B) issue efeat + pack loads for tile i+2 (consumed NEXT iteration at H)
        const int next = tile + (int)gridDim.x;
        const bool has_next = next < NT;
        const int n2 = next + (int)gridDim.x;
        const int tl2 = (n2 < NT) ? n2 : tile;
        const float* np2 = efeat + ((size_t)tl2 * 16 + se) * 128 + sd;
        f32x4 eAn = *(const f32x4*)np2;
        f32x4 eBn = *(const f32x4*)(np2 + 4);
        int4 pk2 = pack[tl2 * 16 + el];

        // C) barrier: order LDS double-buffer only — do NOT drain vmcnt
        asm volatile("s_waitcnt lgkmcnt(0)" ::: "memory");
        __builtin_amdgcn_s_barrier();
        __builtin_amdgcn_sched_barrier(0);

        // D) MFMA phase from LDS (lgkmcnt only)
        __builtin_amdgcn_s_setprio(1);
        f32x4 acc0 = {}, acc1 = {};
#pragma unroll
        for (int kc = 0; kc < 4; ++kc) {
            const int kb = kc * 32 + g * 8;
            bf16x8 bh = *(const bf16x8*)&lds_hi[buf][el][kb];
            bf16x8 bl = *(const bf16x8*)&lds_lo[buf][el][kb];
            acc0 = __builtin_amdgcn_mfma_f32_16x16x32_bf16(wh[0][kc], bh, acc0, 0, 0, 0);
            acc0 = __builtin_amdgcn_mfma_f32_16x16x32_bf16(wh[0][kc], bl, acc0, 0, 0, 0);
            acc0 = __builtin_amdgcn_mfma_f32_16x16x32_bf16(wl[0][kc], bh, acc0, 0, 0, 0);
            acc1 = __builtin_amdgcn_mfma_f32_16x16x32_bf16(wh[1][kc], bh, acc1, 0, 0, 0);
            acc1 = __builtin_amdgcn_mfma_f32_16x16x32_bf16(wh[1][kc], bl, acc1, 0, 0, 0);
            acc1 = __builtin_amdgcn_mfma_f32_16x16x32_bf16(wl[1][kc], bh, acc1, 0, 0, 0);
        }
        __builtin_amdgcn_s_setprio(0);

        // E) combine (gathers have had the MFMA phase to land)
        float part = 0.f;
#pragma unroll
        for (int j = 0; j < 4; ++j) {
            part += q0[j] * k0[j] * acc0[j];
            part += q1[j] * k1[j] * acc1[j];
        }
        part += __shfl_xor(part, 16, 64);
        part += __shfl_xor(part, 32, 64);
        float sc = part * 0.17677669529663687f;     // 1/sqrt(32)
        sc = fminf(5.0f, fmaxf(-5.0f, sc));
        const float a = __expf(sc);

        const int edge = tile * 16 + el;
        if (g == 0) {
            attn_out[(size_t)hw * EN + edge] = a;          // coalesced 64B per wave
            attn_csr[(size_t)pk.z * 4 + hw] = a;           // scattered 4B
        }

        if (!has_next) break;

        // H) write tile i+1 into LDS[buf^1] from eA/eB (loaded a FULL iteration ago —
        //    counted vmcnt wait skips past the newer A/B loads; no stall)
        {
            bf16x8 h8, l8;
#pragma unroll
            for (int j = 0; j < 4; ++j) {
                h8[j] = f2bf(eA[j]);     l8[j] = f2bf(eA[j] - bf2f(h8[j]));
                h8[4 + j] = f2bf(eB[j]); l8[4 + j] = f2bf(eB[j] - bf2f(h8[4 + j]));
            }
            *(bf16x8*)&lds_hi[buf ^ 1][se][sd] = h8;
            *(bf16x8*)&lds_lo[buf ^ 1][se][sd] = l8;
        }

        // rotate pipeline state
        tile = next;
        pk = pk1;  pk1 = pk2;
        eA = eAn;  eB = eBn;
        buf ^= 1;
    }
}

// ---------------- K2b: per-node gather-reduce + W_fc matvec + residual + LN ----------
// 512 threads = 32 nodes/block: one W_fc LDS copy amortized 2x.
__global__ __launch_bounds__(512) void node_kernel(
    const int* __restrict__ base, const int* __restrict__ tgt_csr,
    const float* __restrict__ attn_csr, const short* __restrict__ Vb,
    const short* __restrict__ Wfcb, const float* __restrict__ inQ,
    const float* __restrict__ gamma, const float* __restrict__ beta,
    float* __restrict__ y)
{
    __shared__ short wlds[128 * 136];   // padded: stride 136 bf16
    __shared__ float alds[32 * 132];    // padded: stride 132 f32

    const int t = threadIdx.x;
    // stage W_fc: thread handles row r=t>>2, cols (t&3)*32..+31
    {
        const int r = t >> 2, colb = (t & 3) * 32;
#pragma unroll
        for (int c = 0; c < 4; ++c) {
            bf16x8 w = *(const bf16x8*)(Wfcb + r * 128 + colb + c * 8);
            *(bf16x8*)(&wlds[r * 136 + colb + c * 8]) = w;
        }
    }

    const int n_l = t >> 4;             // 0..31
    const int el  = t & 15;
    const int node = blockIdx.x * 32 + n_l;

    int b0 = 0, b1 = 0;
    if (node < NN) { b0 = base[node]; b1 = base[node + 1]; }
    float acc[8] = {};
    float csum = 0.f;
    const int h = el >> 2;

    int p = b0;
    for (; p + 8 <= b1; p += 8) {      // unroll x8 for memory-level parallelism
        int   tg[8];
        float aa[8];
        bf16x8 vv[8];
#pragma unroll
        for (int u = 0; u < 8; ++u) tg[u] = tgt_csr[p + u];
#pragma unroll
        for (int u = 0; u < 8; ++u) aa[u] = attn_csr[(size_t)(p + u) * 4 + h];
#pragma unroll
        for (int u = 0; u < 8; ++u) vv[u] = *(const bf16x8*)(Vb + (size_t)tg[u] * 128 + el * 8);
#pragma unroll
        for (int u = 0; u < 8; ++u) {
            csum += aa[u];
#pragma unroll
            for (int j = 0; j < 8; ++j) acc[j] += aa[u] * bf2f(vv[u][j]);
        }
    }
    for (; p < b1; ++p) {
        const int tg = tgt_csr[p];
        const float a = attn_csr[(size_t)p * 4 + h];
        bf16x8 v = *(const bf16x8*)(Vb + (size_t)tg * 128 + el * 8);
        csum += a;
#pragma unroll
        for (int j = 0; j < 8; ++j) acc[j] += a * bf2f(v[j]);
    }

    const float invc = 1.0f / (csum + 1e-8f);
#pragma unroll
    for (int j = 0; j < 8; ++j) alds[n_l * 132 + el * 8 + j] = acc[j] * invc;
    __syncthreads();

    float fc[8] = {};
#pragma unroll 4
    for (int k0 = 0; k0 < 128; k0 += 8) {
        float a8[8];
#pragma unroll
        for (int j = 0; j < 8; ++j) a8[j] = alds[n_l * 132 + k0 + j];
#pragma unroll
        for (int i = 0; i < 8; ++i) {
            const int d = el + 16 * i;
            bf16x8 w = *(const bf16x8*)(&wlds[d * 136 + k0]);
#pragma unroll
            for (int j = 0; j < 8; ++j) fc[i] += a8[j] * bf2f(w[j]);
        }
    }

    if (node < NN) {
        float x[8];
        float s = 0.f, s2 = 0.f;
#pragma unroll
        for (int i = 0; i < 8; ++i) {
            const int d = el + 16 * i;
            x[i] = fc[i] + inQ[(size_t)node * 128 + d];
            s += x[i]; s2 += x[i] * x[i];
        }
        s  += __shfl_xor(s, 1, 64);  s2 += __shfl_xor(s2, 1, 64);
        s  += __shfl_xor(s, 2, 64);  s2 += __shfl_xor(s2, 2, 64);
        s  += __shfl_xor(s, 4, 64);  s2 += __shfl_xor(s2, 4, 64);
        s  += __shfl_xor(s, 8, 64);  s2 += __shfl_xor(s2, 8, 64);
        const float mu = s * (1.0f / 128.0f);
        const float var = s2 * (1.0f / 128.0f) - mu * mu;
        const float rstd = rsqrtf(var + 1e-5f);
#pragma unroll
        for (int i = 0; i < 8; ++i) {
            const int d = el + 16 * i;
            y[(size_t)node * 128 + d] = (x[i] - mu) * rstd * gamma[d] + beta[d];
        }
    }
}

// ---------------- launcher ----------------
extern "C" void kernel_launch(void* const* d_in, const int* in_sizes, int n_in,
                              void* d_out, int out_size, void* d_ws, size_t ws_size,
                              hipStream_t stream) {
    const int*   eidx  = (const int*)d_in[0];
    const float* efeat = (const float*)d_in[1];
    const float* inQ   = (const float*)d_in[2];
    const float* inK   = (const float*)d_in[3];
    const float* inV   = (const float*)d_in[4];
    const float* WQ    = (const float*)d_in[5];
    const float* WK    = (const float*)d_in[6];
    const float* WV    = (const float*)d_in[7];
    const float* WE    = (const float*)d_in[8];
    const float* Wfc   = (const float*)d_in[9];
    const float* gamma = (const float*)d_in[10];
    const float* beta  = (const float*)d_in[11];

    float* y = (float*)d_out;
    float* attn_out = y + (size_t)NN * 128;   // 3,200,000

    // ws layout (bytes): same as R6-R12
    char* ws = (char*)d_ws;
    float* Qf      = (float*)ws;
    float* Kf      = (float*)(ws + 12800000);
    short* Vb      = (short*)(ws + 25600000);
    short* Whi     = (short*)(ws + 32000000);
    short* Wlo     = (short*)(ws + 32163840);
    float* attn_csr= (float*)(ws + 32262144);
    int*   tgt_csr = (int*)  (ws + 38662144);
    int4*  pack    = (int4*) (ws + 40262144);
    int*   deg     = (int*)  (ws + 46662144);
    int*   cnt     = (int*)  (ws + 46762496);
    int*   base    = (int*)  (ws + 46862848);

    hipMemsetAsync(deg, 0, 200704, stream);   // deg + cnt

    convert_hist_kernel<<<512 + (EN + 255) / 256, 256, 0, stream>>>(
        WQ, WK, WV, WE, Wfc, Whi, Wlo, eidx, deg);
    scan_kernel<<<1, 1024, 0, stream>>>(deg, base);
    scatter_kernel<<<(EN + 255) / 256, 256, 0, stream>>>(eidx, base, cnt, pack, tgt_csr);

    dim3 pg(391, 3);
    proj_all_kernel<<<pg, 256, 0, stream>>>(inQ, inK, inV, Whi, Wlo, Qf, Kf, Vb);

    edge_score_kernel<<<2048, 256, 0, stream>>>(pack, efeat, Qf, Kf,
                                                Whi + 3 * 16384, Wlo + 2 * 16384,
                                                attn_out, attn_csr);

    node_kernel<<<(NN + 31) / 32, 512, 0, stream>>>(base, tgt_csr, attn_csr, Vb,
                                                    Whi + 4 * 16384, inQ, gamma, beta, y);
}

// Round 14
// 250.390 us; speedup vs baseline: 1.0704x; 1.0213x over previous
//
#include <hip/hip_runtime.h>
#include <hip/hip_bf16.h>
#include <cstdint>
#include <cstddef>

// Problem constants (B=1)
#define EN 400000   // edges
#define NN 25000    // nodes
// D=128, H=4, DK=DV=32

typedef __attribute__((ext_vector_type(8))) short bf16x8;
typedef __attribute__((ext_vector_type(4))) short bf16x4;
typedef __attribute__((ext_vector_type(4))) float f32x4;
typedef __attribute__((ext_vector_type(4))) _Float16 f16x4;

__device__ __forceinline__ short f2bf(float f) {
    unsigned int u = __float_as_uint(f);
    u = (u + 0x7fffu + ((u >> 16) & 1u)) >> 16;   // RNE
    return (short)u;
}
__device__ __forceinline__ float bf2f(short s) {
    return __uint_as_float(((unsigned int)(unsigned short)s) << 16);
}

// Identity ds_bpermute: result is DS-defined, so the compiler cannot rematerialize
// it from the original global load -> weight fragments stay register-resident.
__device__ __forceinline__ bf16x8 pin8(bf16x8 v) {
    union { bf16x8 s; int i[4]; } u; u.s = v;
    const int a = (threadIdx.x & 63) << 2;
#pragma unroll
    for (int k = 0; k < 4; ++k) u.i[k] = __builtin_amdgcn_ds_bpermute(a, u.i[k]);
    return u.s;
}

// ---------------- K0: fused weights->bf16 (hi 5 mats, lo 3 mats) + degree histogram ---
__global__ __launch_bounds__(256) void convert_hist_kernel(
    const float* __restrict__ w0, const float* __restrict__ w1,
    const float* __restrict__ w2, const float* __restrict__ w3,
    const float* __restrict__ w4, short* __restrict__ hi, short* __restrict__ lo,
    const int* __restrict__ eidx, int* __restrict__ deg)
{
    if (blockIdx.x < 512) {
        int i = blockIdx.x * 256 + threadIdx.x;      // 131072 threads
        if (i < 81920) {
            int w = i >> 14, off = i & 16383;
            const float* src = (w == 0) ? w0 : (w == 1) ? w1 : (w == 2) ? w2 : (w == 3) ? w3 : w4;
            hi[i] = f2bf(src[off]);
        } else {
            int j = i - 81920;                       // WQ, WK, WE lo parts
            int m = j >> 14, off = j & 16383;
            const float* src = (m == 0) ? w0 : (m == 1) ? w1 : w3;
            float x = src[off];
            short h = f2bf(x);
            lo[j] = f2bf(x - bf2f(h));
        }
    } else {
        int e = (blockIdx.x - 512) * 256 + threadIdx.x;
        if (e < EN) atomicAdd(&deg[eidx[e]], 1);
    }
}

// ---------------- CSR scan ----------------
__global__ __launch_bounds__(1024) void scan_kernel(
    const int* __restrict__ deg, int* __restrict__ base)
{
    __shared__ int part[1024];
    const int t = threadIdx.x;
    const int CH = 25;                       // 1024*25 = 25600 >= NN
    int loc[CH];
    int s = 0;
#pragma unroll
    for (int i = 0; i < CH; ++i) {
        int idx = t * CH + i;
        loc[i] = s;
        s += (idx < NN) ? deg[idx] : 0;
    }
    part[t] = s;
    __syncthreads();
    for (int d = 1; d < 1024; d <<= 1) {
        int v = (t >= d) ? part[t - d] : 0;
        __syncthreads();
        part[t] += v;
        __syncthreads();
    }
    int off = (t > 0) ? part[t - 1] : 0;
#pragma unroll
    for (int i = 0; i < CH; ++i) {
        int idx = t * CH + i;
        if (idx < NN) base[idx] = off + loc[i];
    }
    if (t == 1023) base[NN] = part[1023];
}

// writes pack[e] = {src, tgt, csr_pos, 0} and tgt_csr[csr_pos] = tgt
__global__ __launch_bounds__(256) void scatter_kernel(
    const int* __restrict__ eidx, const int* __restrict__ base,
    int* __restrict__ cnt, int4* __restrict__ pack, int* __restrict__ tgt_csr)
{
    int e = blockIdx.x * 256 + threadIdx.x;
    if (e < EN) {
        int s = eidx[e];
        int tg = eidx[EN + e];
        int p = base[s] + atomicAdd(&cnt[s], 1);
        pack[e] = make_int4(s, tg, p, 0);
        tgt_csr[p] = tg;
    }
}

// ---------------- K1: fused head-split projections (Q,K split->fp16; V bf16) ----------
// blockIdx.y: 0=Q, 1=K, 2=V. Wave hw = head hw: outdims [32hw, 32hw+32).
// Q,K computed at fp32 precision (split-MFMA) then stored fp16: one 64B cache line
// per (edge,head) slice in the gather -> halves edge-kernel gather traffic.
__global__ __launch_bounds__(256, 4) void proj_all_kernel(
    const float* __restrict__ inQ, const float* __restrict__ inK,
    const float* __restrict__ inV,
    const short* __restrict__ WhiBase, const short* __restrict__ WloBase,
    _Float16* __restrict__ Qh, _Float16* __restrict__ Kh, short* __restrict__ Vb)
{
    const int mode = blockIdx.y;
    const int lane = threadIdx.x & 63;
    const int hw = threadIdx.x >> 6;          // head / wave
    const int el = lane & 15;
    const int g  = lane >> 4;
    const int ntiles = (NN + 15) >> 4;

    if (mode < 2) {
        const float* X = mode ? inK : inQ;
        const short* Whi = WhiBase + mode * 16384;
        const short* Wlo = WloBase + mode * 16384;
        _Float16* P = mode ? Kh : Qh;

        bf16x8 wh[2][4], wl[2][4];
#pragma unroll
        for (int dtt = 0; dtt < 2; ++dtt)
#pragma unroll
            for (int kc = 0; kc < 4; ++kc) {
                const int r = hw * 32 + dtt * 16 + el;
                const int c = kc * 32 + g * 8;
                wh[dtt][kc] = pin8(*(const bf16x8*)(Whi + r * 128 + c));
                wl[dtt][kc] = pin8(*(const bf16x8*)(Wlo + r * 128 + c));
            }

        for (int tile = blockIdx.x; tile < ntiles; tile += gridDim.x) {
            const int row = tile * 16 + el;
            const int rc = row < NN ? row : NN - 1;
            const float* xrow = X + (size_t)rc * 128;
            f32x4 acc0 = {}, acc1 = {};
#pragma unroll
            for (int kc = 0; kc < 4; ++kc) {
                const int kb = kc * 32 + g * 8;
                f32x4 x0 = *(const f32x4*)(xrow + kb);
                f32x4 x1 = *(const f32x4*)(xrow + kb + 4);
                bf16x8 bh, bl;
#pragma unroll
                for (int j = 0; j < 4; ++j) {
                    bh[j] = f2bf(x0[j]); bl[j] = f2bf(x0[j] - bf2f(bh[j]));
                    bh[4 + j] = f2bf(x1[j]); bl[4 + j] = f2bf(x1[j] - bf2f(bh[4 + j]));
                }
                acc0 = __builtin_amdgcn_mfma_f32_16x16x32_bf16(wh[0][kc], bh, acc0, 0, 0, 0);
                acc0 = __builtin_amdgcn_mfma_f32_16x16x32_bf16(wh[0][kc], bl, acc0, 0, 0, 0);
                acc0 = __builtin_amdgcn_mfma_f32_16x16x32_bf16(wl[0][kc], bh, acc0, 0, 0, 0);
                acc1 = __builtin_amdgcn_mfma_f32_16x16x32_bf16(wh[1][kc], bh, acc1, 0, 0, 0);
                acc1 = __builtin_amdgcn_mfma_f32_16x16x32_bf16(wh[1][kc], bl, acc1, 0, 0, 0);
                acc1 = __builtin_amdgcn_mfma_f32_16x16x32_bf16(wl[1][kc], bh, acc1, 0, 0, 0);
            }
            if (row < NN) {
                f16x4 o0, o1;
#pragma unroll
                for (int j = 0; j < 4; ++j) {
                    o0[j] = (_Float16)acc0[j];
                    o1[j] = (_Float16)acc1[j];
                }
                *(f16x4*)(P + (size_t)row * 128 + hw * 32 + g * 4)      = o0;
                *(f16x4*)(P + (size_t)row * 128 + hw * 32 + 16 + g * 4) = o1;
            }
        }
    } else {
        const short* Wb = WhiBase + 2 * 16384;
        bf16x8 wv[2][4];
#pragma unroll
        for (int dtt = 0; dtt < 2; ++dtt)
#pragma unroll
            for (int kc = 0; kc < 4; ++kc)
                wv[dtt][kc] = pin8(*(const bf16x8*)(Wb + (hw * 32 + dtt * 16 + el) * 128 + kc * 32 + g * 8));

        for (int tile = blockIdx.x; tile < ntiles; tile += gridDim.x) {
            const int row = tile * 16 + el;
            const int rc = row < NN ? row : NN - 1;
            const float* xrow = inV + (size_t)rc * 128;
            f32x4 acc0 = {}, acc1 = {};
#pragma unroll
            for (int kc = 0; kc < 4; ++kc) {
                const int kb = kc * 32 + g * 8;
                f32x4 x0 = *(const f32x4*)(xrow + kb);
                f32x4 x1 = *(const f32x4*)(xrow + kb + 4);
                bf16x8 b;
#pragma unroll
                for (int j = 0; j < 4; ++j) { b[j] = f2bf(x0[j]); b[4 + j] = f2bf(x1[j]); }
                acc0 = __builtin_amdgcn_mfma_f32_16x16x32_bf16(wv[0][kc], b, acc0, 0, 0, 0);
                acc1 = __builtin_amdgcn_mfma_f32_16x16x32_bf16(wv[1][kc], b, acc1, 0, 0, 0);
            }
            if (row < NN) {
                bf16x4 o0, o1;
#pragma unroll
                for (int j = 0; j < 4; ++j) { o0[j] = f2bf(acc0[j]); o1[j] = f2bf(acc1[j]); }
                *(bf16x4*)(Vb + (size_t)row * 128 + hw * 32 + g * 4)      = o0;
                *(bf16x4*)(Vb + (size_t)row * 128 + hw * 32 + 16 + g * 4) = o1;
            }
        }
    }
}

// ---------------- K2a: LDS-staged Ef-GEMM + score + exp (fp16 gathers) ----------------
// R13 schedule (write-late staging) + fp16 Q/K gathers: each (edge,head) Q or K slice
// is one 64B line — gather traffic halved vs fp32 (L3-bandwidth-bound per R11-R13
// schedule-insensitivity). Counted-vmcnt barrier (lgkmcnt only). Weights pinned.
__global__ __launch_bounds__(256, 3) void edge_score_kernel(
    const int4* __restrict__ pack, const float* __restrict__ efeat,
    const _Float16* __restrict__ Qh, const _Float16* __restrict__ Kh,
    const short* __restrict__ WEhi, const short* __restrict__ WElo,
    float* __restrict__ attn_out, float* __restrict__ attn_csr)
{
    __shared__ short lds_hi[2][16][136];   // [buf][edge][dim]
    __shared__ short lds_lo[2][16][136];

    const int t    = threadIdx.x;
    const int lane = t & 63;
    const int hw   = t >> 6;              // head / wave
    const int el   = lane & 15;
    const int g    = lane >> 4;
    const int se   = t >> 4;              // staging: edge 0..15
    const int sd   = (t & 15) * 8;        // staging: dim
    const int NT   = EN / 16;

    // pinned weight fragments
    bf16x8 wh[2][4], wl[2][4];
#pragma unroll
    for (int dtt = 0; dtt < 2; ++dtt)
#pragma unroll
        for (int kc = 0; kc < 4; ++kc) {
            const int r = hw * 32 + dtt * 16 + el;
            const int c = kc * 32 + g * 8;
            wh[dtt][kc] = pin8(*(const bf16x8*)(WEhi + r * 128 + c));
            wl[dtt][kc] = pin8(*(const bf16x8*)(WElo + r * 128 + c));
        }

    const int dbase = hw * 32 + g * 4;
    int tile = blockIdx.x;
    int4 pk = pack[tile * 16 + el];

    // prologue: synchronous stage tile0 -> LDS[0]
    {
        const float* p = efeat + ((size_t)tile * 16 + se) * 128 + sd;
        f32x4 a = *(const f32x4*)p;
        f32x4 b = *(const f32x4*)(p + 4);
        bf16x8 h8, l8;
#pragma unroll
        for (int j = 0; j < 4; ++j) {
            h8[j] = f2bf(a[j]);     l8[j] = f2bf(a[j] - bf2f(h8[j]));
            h8[4 + j] = f2bf(b[j]); l8[4 + j] = f2bf(b[j] - bf2f(h8[4 + j]));
        }
        *(bf16x8*)&lds_hi[0][se][sd] = h8;
        *(bf16x8*)&lds_lo[0][se][sd] = l8;
    }
    // preload tile1 data into registers (written to LDS at end of iteration 0)
    f32x4 eA, eB;
    int4 pk1;
    {
        const int t1 = tile + (int)gridDim.x;
        const int tl1 = (t1 < NT) ? t1 : tile;
        const float* np = efeat + ((size_t)tl1 * 16 + se) * 128 + sd;
        eA = *(const f32x4*)np;
        eB = *(const f32x4*)(np + 4);
        pk1 = pack[tl1 * 16 + el];
    }

    int buf = 0;
    while (true) {
        // A) fp16 gathers for CURRENT tile (consumed at E, after the MFMA phase)
        const _Float16* qrow = Qh + (size_t)pk.x * 128 + dbase;
        const _Float16* krow = Kh + (size_t)pk.y * 128 + dbase;
        f16x4 q0 = *(const f16x4*)(qrow);
        f16x4 q1 = *(const f16x4*)(qrow + 16);
        f16x4 k0 = *(const f16x4*)(krow);
        f16x4 k1 = *(const f16x4*)(krow + 16);

        // B) issue efeat + pack loads for tile i+2 (consumed NEXT iteration at H)
        const int next = tile + (int)gridDim.x;
        const bool has_next = next < NT;
        const int n2 = next + (int)gridDim.x;
        const int tl2 = (n2 < NT) ? n2 : tile;
        const float* np2 = efeat + ((size_t)tl2 * 16 + se) * 128 + sd;
        f32x4 eAn = *(const f32x4*)np2;
        f32x4 eBn = *(const f32x4*)(np2 + 4);
        int4 pk2 = pack[tl2 * 16 + el];

        // C) barrier: order LDS double-buffer only — do NOT drain vmcnt
        asm volatile("s_waitcnt lgkmcnt(0)" ::: "memory");
        __builtin_amdgcn_s_barrier();
        __builtin_amdgcn_sched_barrier(0);

        // D) MFMA phase from LDS (lgkmcnt only)
        __builtin_amdgcn_s_setprio(1);
        f32x4 acc0 = {}, acc1 = {};
#pragma unroll
        for (int kc = 0; kc < 4; ++kc) {
            const int kb = kc * 32 + g * 8;
            bf16x8 bh = *(const bf16x8*)&lds_hi[buf][el][kb];
            bf16x8 bl = *(const bf16x8*)&lds_lo[buf][el][kb];
            acc0 = __builtin_amdgcn_mfma_f32_16x16x32_bf16(wh[0][kc], bh, acc0, 0, 0, 0);
            acc0 = __builtin_amdgcn_mfma_f32_16x16x32_bf16(wh[0][kc], bl, acc0, 0, 0, 0);
            acc0 = __builtin_amdgcn_mfma_f32_16x16x32_bf16(wl[0][kc], bh, acc0, 0, 0, 0);
            acc1 = __builtin_amdgcn_mfma_f32_16x16x32_bf16(wh[1][kc], bh, acc1, 0, 0, 0);
            acc1 = __builtin_amdgcn_mfma_f32_16x16x32_bf16(wh[1][kc], bl, acc1, 0, 0, 0);
            acc1 = __builtin_amdgcn_mfma_f32_16x16x32_bf16(wl[1][kc], bh, acc1, 0, 0, 0);
        }
        __builtin_amdgcn_s_setprio(0);

        // E) combine (gathers have had the MFMA phase to land)
        float part = 0.f;
#pragma unroll
        for (int j = 0; j < 4; ++j) {
            part += (float)q0[j] * (float)k0[j] * acc0[j];
            part += (float)q1[j] * (float)k1[j] * acc1[j];
        }
        part += __shfl_xor(part, 16, 64);
        part += __shfl_xor(part, 32, 64);
        float sc = part * 0.17677669529663687f;     // 1/sqrt(32)
        sc = fminf(5.0f, fmaxf(-5.0f, sc));
        const float a = __expf(sc);

        const int edge = tile * 16 + el;
        if (g == 0) {
            attn_out[(size_t)hw * EN + edge] = a;          // coalesced 64B per wave
            attn_csr[(size_t)pk.z * 4 + hw] = a;           // scattered 4B
        }

        if (!has_next) break;

        // H) write tile i+1 into LDS[buf^1] from eA/eB (loaded a FULL iteration ago)
        {
            bf16x8 h8, l8;
#pragma unroll
            for (int j = 0; j < 4; ++j) {
                h8[j] = f2bf(eA[j]);     l8[j] = f2bf(eA[j] - bf2f(h8[j]));
                h8[4 + j] = f2bf(eB[j]); l8[4 + j] = f2bf(eB[j] - bf2f(h8[4 + j]));
            }
            *(bf16x8*)&lds_hi[buf ^ 1][se][sd] = h8;
            *(bf16x8*)&lds_lo[buf ^ 1][se][sd] = l8;
        }

        // rotate pipeline state
        tile = next;
        pk = pk1;  pk1 = pk2;
        eA = eAn;  eB = eBn;
        buf ^= 1;
    }
}

// ---------------- K2b: per-node gather-reduce + W_fc matvec + residual + LN ----------
// 512 threads = 32 nodes/block: one W_fc LDS copy amortized 2x.
__global__ __launch_bounds__(512) void node_kernel(
    const int* __restrict__ base, const int* __restrict__ tgt_csr,
    const float* __restrict__ attn_csr, const short* __restrict__ Vb,
    const short* __restrict__ Wfcb, const float* __restrict__ inQ,
    const float* __restrict__ gamma, const float* __restrict__ beta,
    float* __restrict__ y)
{
    __shared__ short wlds[128 * 136];   // padded: stride 136 bf16
    __shared__ float alds[32 * 132];    // padded: stride 132 f32

    const int t = threadIdx.x;
    // stage W_fc: thread handles row r=t>>2, cols (t&3)*32..+31
    {
        const int r = t >> 2, colb = (t & 3) * 32;
#pragma unroll
        for (int c = 0; c < 4; ++c) {
            bf16x8 w = *(const bf16x8*)(Wfcb + r * 128 + colb + c * 8);
            *(bf16x8*)(&wlds[r * 136 + colb + c * 8]) = w;
        }
    }

    const int n_l = t >> 4;             // 0..31
    const int el  = t & 15;
    const int node = blockIdx.x * 32 + n_l;

    int b0 = 0, b1 = 0;
    if (node < NN) { b0 = base[node]; b1 = base[node + 1]; }
    float acc[8] = {};
    float csum = 0.f;
    const int h = el >> 2;

    int p = b0;
    for (; p + 8 <= b1; p += 8) {      // unroll x8 for memory-level parallelism
        int   tg[8];
        float aa[8];
        bf16x8 vv[8];
#pragma unroll
        for (int u = 0; u < 8; ++u) tg[u] = tgt_csr[p + u];
#pragma unroll
        for (int u = 0; u < 8; ++u) aa[u] = attn_csr[(size_t)(p + u) * 4 + h];
#pragma unroll
        for (int u = 0; u < 8; ++u) vv[u] = *(const bf16x8*)(Vb + (size_t)tg[u] * 128 + el * 8);
#pragma unroll
        for (int u = 0; u < 8; ++u) {
            csum += aa[u];
#pragma unroll
            for (int j = 0; j < 8; ++j) acc[j] += aa[u] * bf2f(vv[u][j]);
        }
    }
    for (; p < b1; ++p) {
        const int tg = tgt_csr[p];
        const float a = attn_csr[(size_t)p * 4 + h];
        bf16x8 v = *(const bf16x8*)(Vb + (size_t)tg * 128 + el * 8);
        csum += a;
#pragma unroll
        for (int j = 0; j < 8; ++j) acc[j] += a * bf2f(v[j]);
    }

    const float invc = 1.0f / (csum + 1e-8f);
#pragma unroll
    for (int j = 0; j < 8; ++j) alds[n_l * 132 + el * 8 + j] = acc[j] * invc;
    __syncthreads();

    float fc[8] = {};
#pragma unroll 4
    for (int k0 = 0; k0 < 128; k0 += 8) {
        float a8[8];
#pragma unroll
        for (int j = 0; j < 8; ++j) a8[j] = alds[n_l * 132 + k0 + j];
#pragma unroll
        for (int i = 0; i < 8; ++i) {
            const int d = el + 16 * i;
            bf16x8 w = *(const bf16x8*)(&wlds[d * 136 + k0]);
#pragma unroll
            for (int j = 0; j < 8; ++j) fc[i] += a8[j] * bf2f(w[j]);
        }
    }

    if (node < NN) {
        float x[8];
        float s = 0.f, s2 = 0.f;
#pragma unroll
        for (int i = 0; i < 8; ++i) {
            const int d = el + 16 * i;
            x[i] = fc[i] + inQ[(size_t)node * 128 + d];
            s += x[i]; s2 += x[i] * x[i];
        }
        s  += __shfl_xor(s, 1, 64);  s2 += __shfl_xor(s2, 1, 64);
        s  += __shfl_xor(s, 2, 64);  s2 += __shfl_xor(s2, 2, 64);
        s  += __shfl_xor(s, 4, 64);  s2 += __shfl_xor(s2, 4, 64);
        s  += __shfl_xor(s, 8, 64);  s2 += __shfl_xor(s2, 8, 64);
        const float mu = s * (1.0f / 128.0f);
        const float var = s2 * (1.0f / 128.0f) - mu * mu;
        const float rstd = rsqrtf(var + 1e-5f);
#pragma unroll
        for (int i = 0; i < 8; ++i) {
            const int d = el + 16 * i;
            y[(size_t)node * 128 + d] = (x[i] - mu) * rstd * gamma[d] + beta[d];
        }
    }
}

// ---------------- launcher ----------------
extern "C" void kernel_launch(void* const* d_in, const int* in_sizes, int n_in,
                              void* d_out, int out_size, void* d_ws, size_t ws_size,
                              hipStream_t stream) {
    const int*   eidx  = (const int*)d_in[0];
    const float* efeat = (const float*)d_in[1];
    const float* inQ   = (const float*)d_in[2];
    const float* inK   = (const float*)d_in[3];
    const float* inV   = (const float*)d_in[4];
    const float* WQ    = (const float*)d_in[5];
    const float* WK    = (const float*)d_in[6];
    const float* WV    = (const float*)d_in[7];
    const float* WE    = (const float*)d_in[8];
    const float* Wfc   = (const float*)d_in[9];
    const float* gamma = (const float*)d_in[10];
    const float* beta  = (const float*)d_in[11];

    float* y = (float*)d_out;
    float* attn_out = y + (size_t)NN * 128;   // 3,200,000

    // ws layout (bytes):
    //   Qh fp16 (25000x128):   6,400,000 @ 0
    //   Kh fp16:               6,400,000 @ 6,400,000
    //   Vb bf16:               6,400,000 @ 12,800,000
    //   Whi (5x16384):           163,840 @ 19,200,000
    //   Wlo (3x16384):            98,304 @ 19,363,840
    //   attn_csr f32:          6,400,000 @ 19,462,144
    //   tgt_csr int:           1,600,000 @ 25,862,144
    //   pack int4:             6,400,000 @ 27,462,144
    //   deg int:                 100,352 @ 33,862,144
    //   cnt int:                 100,352 @ 33,962,496
    //   base int (NN+1):         100,352 @ 34,062,848  -> total 34,163,200
    char* ws = (char*)d_ws;
    _Float16* Qh   = (_Float16*)ws;
    _Float16* Kh   = (_Float16*)(ws + 6400000);
    short* Vb      = (short*)(ws + 12800000);
    short* Whi     = (short*)(ws + 19200000);
    short* Wlo     = (short*)(ws + 19363840);
    float* attn_csr= (float*)(ws + 19462144);
    int*   tgt_csr = (int*)  (ws + 25862144);
    int4*  pack    = (int4*) (ws + 27462144);
    int*   deg     = (int*)  (ws + 33862144);
    int*   cnt     = (int*)  (ws + 33962496);
    int*   base    = (int*)  (ws + 34062848);

    hipMemsetAsync(deg, 0, 200704, stream);   // deg + cnt

    convert_hist_kernel<<<512 + (EN + 255) / 256, 256, 0, stream>>>(
        WQ, WK, WV, WE, Wfc, Whi, Wlo, eidx, deg);
    scan_kernel<<<1, 1024, 0, stream>>>(deg, base);
    scatter_kernel<<<(EN + 255) / 256, 256, 0, stream>>>(eidx, base, cnt, pack, tgt_csr);

    dim3 pg(391, 3);
    proj_all_kernel<<<pg, 256, 0, stream>>>(inQ, inK, inV, Whi, Wlo, Qh, Kh, Vb);

    edge_score_kernel<<<2048, 256, 0, stream>>>(pack, efeat, Qh, Kh,
                                                Whi + 3 * 16384, Wlo + 2 * 16384,
                                                attn_out, attn_csr);

    node_kernel<<<(NN + 31) / 32, 512, 0, stream>>>(base, tgt_csr, attn_csr, Vb,
                                                    Whi + 4 * 16384, inQ, gamma, beta, y);
}

// Round 15
// 240.719 us; speedup vs baseline: 1.1134x; 1.0402x over previous
//
#include <hip/hip_runtime.h>
#include <hip/hip_bf16.h>
#include <cstdint>
#include <cstddef>

// Problem constants (B=1)
#define EN 400000   // edges
#define NN 25000    // nodes
// D=128, H=4, DK=DV=32

typedef __attribute__((ext_vector_type(8))) short bf16x8;
typedef __attribute__((ext_vector_type(4))) short bf16x4;
typedef __attribute__((ext_vector_type(4))) float f32x4;
typedef __attribute__((ext_vector_type(4))) _Float16 f16x4;
typedef __attribute__((ext_vector_type(8))) _Float16 f16x8;

__device__ __forceinline__ short f2bf(float f) {
    unsigned int u = __float_as_uint(f);
    u = (u + 0x7fffu + ((u >> 16) & 1u)) >> 16;   // RNE
    return (short)u;
}
__device__ __forceinline__ float bf2f(short s) {
    return __uint_as_float(((unsigned int)(unsigned short)s) << 16);
}

// Identity ds_bpermute: result is DS-defined, so the compiler cannot rematerialize
// it from the original global load -> weight fragments stay register-resident.
__device__ __forceinline__ bf16x8 pin8(bf16x8 v) {
    union { bf16x8 s; int i[4]; } u; u.s = v;
    const int a = (threadIdx.x & 63) << 2;
#pragma unroll
    for (int k = 0; k < 4; ++k) u.i[k] = __builtin_amdgcn_ds_bpermute(a, u.i[k]);
    return u.s;
}
__device__ __forceinline__ f16x8 pin8h(f16x8 v) {
    union { f16x8 s; int i[4]; } u; u.s = v;
    const int a = (threadIdx.x & 63) << 2;
#pragma unroll
    for (int k = 0; k < 4; ++k) u.i[k] = __builtin_amdgcn_ds_bpermute(a, u.i[k]);
    return u.s;
}

// ---------------- K0: weights->bf16 hi/lo + WE->fp16 + degree histogram ----------------
__global__ __launch_bounds__(256) void convert_hist_kernel(
    const float* __restrict__ w0, const float* __restrict__ w1,
    const float* __restrict__ w2, const float* __restrict__ w3,
    const float* __restrict__ w4, short* __restrict__ hi, short* __restrict__ lo,
    _Float16* __restrict__ wef,
    const int* __restrict__ eidx, int* __restrict__ deg)
{
    if (blockIdx.x < 576) {
        int i = blockIdx.x * 256 + threadIdx.x;      // 147456 threads
        if (i < 81920) {
            int w = i >> 14, off = i & 16383;
            const float* src = (w == 0) ? w0 : (w == 1) ? w1 : (w == 2) ? w2 : (w == 3) ? w3 : w4;
            hi[i] = f2bf(src[off]);
        } else if (i < 131072) {
            int j = i - 81920;                       // WQ, WK, WE lo parts (bf16)
            int m = j >> 14, off = j & 16383;
            const float* src = (m == 0) ? w0 : (m == 1) ? w1 : w3;
            float x = src[off];
            short h = f2bf(x);
            lo[j] = f2bf(x - bf2f(h));
        } else {
            int off = i - 131072;                    // WE -> fp16 (single-pass edge MFMA)
            wef[off] = (_Float16)w3[off];
        }
    } else {
        int e = (blockIdx.x - 576) * 256 + threadIdx.x;
        if (e < EN) atomicAdd(&deg[eidx[e]], 1);
    }
}

// ---------------- CSR scan ----------------
__global__ __launch_bounds__(1024) void scan_kernel(
    const int* __restrict__ deg, int* __restrict__ base)
{
    __shared__ int part[1024];
    const int t = threadIdx.x;
    const int CH = 25;                       // 1024*25 = 25600 >= NN
    int loc[CH];
    int s = 0;
#pragma unroll
    for (int i = 0; i < CH; ++i) {
        int idx = t * CH + i;
        loc[i] = s;
        s += (idx < NN) ? deg[idx] : 0;
    }
    part[t] = s;
    __syncthreads();
    for (int d = 1; d < 1024; d <<= 1) {
        int v = (t >= d) ? part[t - d] : 0;
        __syncthreads();
        part[t] += v;
        __syncthreads();
    }
    int off = (t > 0) ? part[t - 1] : 0;
#pragma unroll
    for (int i = 0; i < CH; ++i) {
        int idx = t * CH + i;
        if (idx < NN) base[idx] = off + loc[i];
    }
    if (t == 1023) base[NN] = part[1023];
}

// writes pack[e] = {src, tgt, csr_pos, 0} and tgt_csr[csr_pos] = tgt
__global__ __launch_bounds__(256) void scatter_kernel(
    const int* __restrict__ eidx, const int* __restrict__ base,
    int* __restrict__ cnt, int4* __restrict__ pack, int* __restrict__ tgt_csr)
{
    int e = blockIdx.x * 256 + threadIdx.x;
    if (e < EN) {
        int s = eidx[e];
        int tg = eidx[EN + e];
        int p = base[s] + atomicAdd(&cnt[s], 1);
        pack[e] = make_int4(s, tg, p, 0);
        tgt_csr[p] = tg;
    }
}

// ---------------- K1: fused head-split projections (Q,K split->fp16; V bf16) ----------
// blockIdx.y: 0=Q, 1=K, 2=V. Wave hw = head hw: outdims [32hw, 32hw+32).
// Q,K computed at fp32 precision (split-MFMA) then stored fp16.
__global__ __launch_bounds__(256, 4) void proj_all_kernel(
    const float* __restrict__ inQ, const float* __restrict__ inK,
    const float* __restrict__ inV,
    const short* __restrict__ WhiBase, const short* __restrict__ WloBase,
    _Float16* __restrict__ Qh, _Float16* __restrict__ Kh, short* __restrict__ Vb)
{
    const int mode = blockIdx.y;
    const int lane = threadIdx.x & 63;
    const int hw = threadIdx.x >> 6;          // head / wave
    const int el = lane & 15;
    const int g  = lane >> 4;
    const int ntiles = (NN + 15) >> 4;

    if (mode < 2) {
        const float* X = mode ? inK : inQ;
        const short* Whi = WhiBase + mode * 16384;
        const short* Wlo = WloBase + mode * 16384;
        _Float16* P = mode ? Kh : Qh;

        bf16x8 wh[2][4], wl[2][4];
#pragma unroll
        for (int dtt = 0; dtt < 2; ++dtt)
#pragma unroll
            for (int kc = 0; kc < 4; ++kc) {
                const int r = hw * 32 + dtt * 16 + el;
                const int c = kc * 32 + g * 8;
                wh[dtt][kc] = pin8(*(const bf16x8*)(Whi + r * 128 + c));
                wl[dtt][kc] = pin8(*(const bf16x8*)(Wlo + r * 128 + c));
            }

        for (int tile = blockIdx.x; tile < ntiles; tile += gridDim.x) {
            const int row = tile * 16 + el;
            const int rc = row < NN ? row : NN - 1;
            const float* xrow = X + (size_t)rc * 128;
            f32x4 acc0 = {}, acc1 = {};
#pragma unroll
            for (int kc = 0; kc < 4; ++kc) {
                const int kb = kc * 32 + g * 8;
                f32x4 x0 = *(const f32x4*)(xrow + kb);
                f32x4 x1 = *(const f32x4*)(xrow + kb + 4);
                bf16x8 bh, bl;
#pragma unroll
                for (int j = 0; j < 4; ++j) {
                    bh[j] = f2bf(x0[j]); bl[j] = f2bf(x0[j] - bf2f(bh[j]));
                    bh[4 + j] = f2bf(x1[j]); bl[4 + j] = f2bf(x1[j] - bf2f(bh[4 + j]));
                }
                acc0 = __builtin_amdgcn_mfma_f32_16x16x32_bf16(wh[0][kc], bh, acc0, 0, 0, 0);
                acc0 = __builtin_amdgcn_mfma_f32_16x16x32_bf16(wh[0][kc], bl, acc0, 0, 0, 0);
                acc0 = __builtin_amdgcn_mfma_f32_16x16x32_bf16(wl[0][kc], bh, acc0, 0, 0, 0);
                acc1 = __builtin_amdgcn_mfma_f32_16x16x32_bf16(wh[1][kc], bh, acc1, 0, 0, 0);
                acc1 = __builtin_amdgcn_mfma_f32_16x16x32_bf16(wh[1][kc], bl, acc1, 0, 0, 0);
                acc1 = __builtin_amdgcn_mfma_f32_16x16x32_bf16(wl[1][kc], bh, acc1, 0, 0, 0);
            }
            if (row < NN) {
                f16x4 o0, o1;
#pragma unroll
                for (int j = 0; j < 4; ++j) {
                    o0[j] = (_Float16)acc0[j];
                    o1[j] = (_Float16)acc1[j];
                }
                *(f16x4*)(P + (size_t)row * 128 + hw * 32 + g * 4)      = o0;
                *(f16x4*)(P + (size_t)row * 128 + hw * 32 + 16 + g * 4) = o1;
            }
        }
    } else {
        const short* Wb = WhiBase + 2 * 16384;
        bf16x8 wv[2][4];
#pragma unroll
        for (int dtt = 0; dtt < 2; ++dtt)
#pragma unroll
            for (int kc = 0; kc < 4; ++kc)
                wv[dtt][kc] = pin8(*(const bf16x8*)(Wb + (hw * 32 + dtt * 16 + el) * 128 + kc * 32 + g * 8));

        for (int tile = blockIdx.x; tile < ntiles; tile += gridDim.x) {
            const int row = tile * 16 + el;
            const int rc = row < NN ? row : NN - 1;
            const float* xrow = inV + (size_t)rc * 128;
            f32x4 acc0 = {}, acc1 = {};
#pragma unroll
            for (int kc = 0; kc < 4; ++kc) {
                const int kb = kc * 32 + g * 8;
                f32x4 x0 = *(const f32x4*)(xrow + kb);
                f32x4 x1 = *(const f32x4*)(xrow + kb + 4);
                bf16x8 b;
#pragma unroll
                for (int j = 0; j < 4; ++j) { b[j] = f2bf(x0[j]); b[4 + j] = f2bf(x1[j]); }
                acc0 = __builtin_amdgcn_mfma_f32_16x16x32_bf16(wv[0][kc], b, acc0, 0, 0, 0);
                acc1 = __builtin_amdgcn_mfma_f32_16x16x32_bf16(wv[1][kc], b, acc1, 0, 0, 0);
            }
            if (row < NN) {
                bf16x4 o0, o1;
#pragma unroll
                for (int j = 0; j < 4; ++j) { o0[j] = f2bf(acc0[j]); o1[j] = f2bf(acc1[j]); }
                *(bf16x4*)(Vb + (size_t)row * 128 + hw * 32 + g * 4)      = o0;
                *(bf16x4*)(Vb + (size_t)row * 128 + hw * 32 + 16 + g * 4) = o1;
            }
        }
    }
}

// ---------------- K2a: single-pass fp16 Ef-GEMM + score + exp ----------------
// fp16 needs no hi/lo split (11-bit mantissa): 8 MFMAs/iter (was 24), 32 pinned regs
// (was 64), staging = 8 native v_cvt (was ~50 VALU of RNE-bf16). Register total ~95
// -> 5 waves/SIMD (was 3). R13 write-late staging + counted-vmcnt barrier retained.
__global__ __launch_bounds__(256, 4) void edge_score_kernel(
    const int4* __restrict__ pack, const float* __restrict__ efeat,
    const _Float16* __restrict__ Qh, const _Float16* __restrict__ Kh,
    const _Float16* __restrict__ WEf,
    float* __restrict__ attn_out, float* __restrict__ attn_csr)
{
    __shared__ _Float16 lds_e[2][16][136];   // [buf][edge][dim], 8.7 KB total

    const int t    = threadIdx.x;
    const int lane = t & 63;
    const int hw   = t >> 6;              // head / wave
    const int el   = lane & 15;
    const int g    = lane >> 4;
    const int se   = t >> 4;              // staging: edge 0..15
    const int sd   = (t & 15) * 8;        // staging: dim
    const int NT   = EN / 16;

    // pinned fp16 weight fragments (32 regs)
    f16x8 wf[2][4];
#pragma unroll
    for (int dtt = 0; dtt < 2; ++dtt)
#pragma unroll
        for (int kc = 0; kc < 4; ++kc) {
            const int r = hw * 32 + dtt * 16 + el;
            const int c = kc * 32 + g * 8;
            wf[dtt][kc] = pin8h(*(const f16x8*)(WEf + r * 128 + c));
        }

    const int dbase = hw * 32 + g * 4;
    int tile = blockIdx.x;
    int4 pk = pack[tile * 16 + el];

    // prologue: synchronous stage tile0 -> LDS[0]
    {
        const float* p = efeat + ((size_t)tile * 16 + se) * 128 + sd;
        f32x4 a = *(const f32x4*)p;
        f32x4 b = *(const f32x4*)(p + 4);
        f16x8 h8;
#pragma unroll
        for (int j = 0; j < 4; ++j) {
            h8[j] = (_Float16)a[j];
            h8[4 + j] = (_Float16)b[j];
        }
        *(f16x8*)&lds_e[0][se][sd] = h8;
    }
    // preload tile1 data into registers (written to LDS at end of iteration 0)
    f32x4 eA, eB;
    int4 pk1;
    {
        const int t1 = tile + (int)gridDim.x;
        const int tl1 = (t1 < NT) ? t1 : tile;
        const float* np = efeat + ((size_t)tl1 * 16 + se) * 128 + sd;
        eA = *(const f32x4*)np;
        eB = *(const f32x4*)(np + 4);
        pk1 = pack[tl1 * 16 + el];
    }

    int buf = 0;
    while (true) {
        // A) fp16 gathers for CURRENT tile (consumed at E, after the MFMA phase)
        const _Float16* qrow = Qh + (size_t)pk.x * 128 + dbase;
        const _Float16* krow = Kh + (size_t)pk.y * 128 + dbase;
        f16x4 q0 = *(const f16x4*)(qrow);
        f16x4 q1 = *(const f16x4*)(qrow + 16);
        f16x4 k0 = *(const f16x4*)(krow);
        f16x4 k1 = *(const f16x4*)(krow + 16);

        // B) issue efeat + pack loads for tile i+2 (consumed NEXT iteration at H)
        const int next = tile + (int)gridDim.x;
        const bool has_next = next < NT;
        const int n2 = next + (int)gridDim.x;
        const int tl2 = (n2 < NT) ? n2 : tile;
        const float* np2 = efeat + ((size_t)tl2 * 16 + se) * 128 + sd;
        f32x4 eAn = *(const f32x4*)np2;
        f32x4 eBn = *(const f32x4*)(np2 + 4);
        int4 pk2 = pack[tl2 * 16 + el];

        // C) barrier: order LDS double-buffer only — do NOT drain vmcnt
        asm volatile("s_waitcnt lgkmcnt(0)" ::: "memory");
        __builtin_amdgcn_s_barrier();
        __builtin_amdgcn_sched_barrier(0);

        // D) MFMA phase from LDS (lgkmcnt only): 8 fp16 MFMAs
        __builtin_amdgcn_s_setprio(1);
        f32x4 acc0 = {}, acc1 = {};
#pragma unroll
        for (int kc = 0; kc < 4; ++kc) {
            const int kb = kc * 32 + g * 8;
            f16x8 be = *(const f16x8*)&lds_e[buf][el][kb];
            acc0 = __builtin_amdgcn_mfma_f32_16x16x32_f16(wf[0][kc], be, acc0, 0, 0, 0);
            acc1 = __builtin_amdgcn_mfma_f32_16x16x32_f16(wf[1][kc], be, acc1, 0, 0, 0);
        }
        __builtin_amdgcn_s_setprio(0);

        // E) combine (gathers have had the MFMA phase to land)
        float part = 0.f;
#pragma unroll
        for (int j = 0; j < 4; ++j) {
            part += (float)q0[j] * (float)k0[j] * acc0[j];
            part += (float)q1[j] * (float)k1[j] * acc1[j];
        }
        part += __shfl_xor(part, 16, 64);
        part += __shfl_xor(part, 32, 64);
        float sc = part * 0.17677669529663687f;     // 1/sqrt(32)
        sc = fminf(5.0f, fmaxf(-5.0f, sc));
        const float a = __expf(sc);

        const int edge = tile * 16 + el;
        if (g == 0) {
            attn_out[(size_t)hw * EN + edge] = a;          // coalesced 64B per wave
            attn_csr[(size_t)pk.z * 4 + hw] = a;           // scattered 4B
        }

        if (!has_next) break;

        // H) write tile i+1 into LDS[buf^1] from eA/eB (loaded a FULL iteration ago)
        {
            f16x8 h8;
#pragma unroll
            for (int j = 0; j < 4; ++j) {
                h8[j] = (_Float16)eA[j];
                h8[4 + j] = (_Float16)eB[j];
            }
            *(f16x8*)&lds_e[buf ^ 1][se][sd] = h8;
        }

        // rotate pipeline state
        tile = next;
        pk = pk1;  pk1 = pk2;
        eA = eAn;  eB = eBn;
        buf ^= 1;
    }
}

// ---------------- K2b: per-node gather-reduce + W_fc matvec + residual + LN ----------
// 512 threads = 32 nodes/block: one W_fc LDS copy amortized 2x.
__global__ __launch_bounds__(512) void node_kernel(
    const int* __restrict__ base, const int* __restrict__ tgt_csr,
    const float* __restrict__ attn_csr, const short* __restrict__ Vb,
    const short* __restrict__ Wfcb, const float* __restrict__ inQ,
    const float* __restrict__ gamma, const float* __restrict__ beta,
    float* __restrict__ y)
{
    __shared__ short wlds[128 * 136];   // padded: stride 136 bf16
    __shared__ float alds[32 * 132];    // padded: stride 132 f32

    const int t = threadIdx.x;
    // stage W_fc: thread handles row r=t>>2, cols (t&3)*32..+31
    {
        const int r = t >> 2, colb = (t & 3) * 32;
#pragma unroll
        for (int c = 0; c < 4; ++c) {
            bf16x8 w = *(const bf16x8*)(Wfcb + r * 128 + colb + c * 8);
            *(bf16x8*)(&wlds[r * 136 + colb + c * 8]) = w;
        }
    }

    const int n_l = t >> 4;             // 0..31
    const int el  = t & 15;
    const int node = blockIdx.x * 32 + n_l;

    int b0 = 0, b1 = 0;
    if (node < NN) { b0 = base[node]; b1 = base[node + 1]; }
    float acc[8] = {};
    float csum = 0.f;
    const int h = el >> 2;

    int p = b0;
    for (; p + 8 <= b1; p += 8) {      // unroll x8 for memory-level parallelism
        int   tg[8];
        float aa[8];
        bf16x8 vv[8];
#pragma unroll
        for (int u = 0; u < 8; ++u) tg[u] = tgt_csr[p + u];
#pragma unroll
        for (int u = 0; u < 8; ++u) aa[u] = attn_csr[(size_t)(p + u) * 4 + h];
#pragma unroll
        for (int u = 0; u < 8; ++u) vv[u] = *(const bf16x8*)(Vb + (size_t)tg[u] * 128 + el * 8);
#pragma unroll
        for (int u = 0; u < 8; ++u) {
            csum += aa[u];
#pragma unroll
            for (int j = 0; j < 8; ++j) acc[j] += aa[u] * bf2f(vv[u][j]);
        }
    }
    for (; p < b1; ++p) {
        const int tg = tgt_csr[p];
        const float a = attn_csr[(size_t)p * 4 + h];
        bf16x8 v = *(const bf16x8*)(Vb + (size_t)tg * 128 + el * 8);
        csum += a;
#pragma unroll
        for (int j = 0; j < 8; ++j) acc[j] += a * bf2f(v[j]);
    }

    const float invc = 1.0f / (csum + 1e-8f);
#pragma unroll
    for (int j = 0; j < 8; ++j) alds[n_l * 132 + el * 8 + j] = acc[j] * invc;
    __syncthreads();

    float fc[8] = {};
#pragma unroll 4
    for (int k0 = 0; k0 < 128; k0 += 8) {
        float a8[8];
#pragma unroll
        for (int j = 0; j < 8; ++j) a8[j] = alds[n_l * 132 + k0 + j];
#pragma unroll
        for (int i = 0; i < 8; ++i) {
            const int d = el + 16 * i;
            bf16x8 w = *(const bf16x8*)(&wlds[d * 136 + k0]);
#pragma unroll
            for (int j = 0; j < 8; ++j) fc[i] += a8[j] * bf2f(w[j]);
        }
    }

    if (node < NN) {
        float x[8];
        float s = 0.f, s2 = 0.f;
#pragma unroll
        for (int i = 0; i < 8; ++i) {
            const int d = el + 16 * i;
            x[i] = fc[i] + inQ[(size_t)node * 128 + d];
            s += x[i]; s2 += x[i] * x[i];
        }
        s  += __shfl_xor(s, 1, 64);  s2 += __shfl_xor(s2, 1, 64);
        s  += __shfl_xor(s, 2, 64);  s2 += __shfl_xor(s2, 2, 64);
        s  += __shfl_xor(s, 4, 64);  s2 += __shfl_xor(s2, 4, 64);
        s  += __shfl_xor(s, 8, 64);  s2 += __shfl_xor(s2, 8, 64);
        const float mu = s * (1.0f / 128.0f);
        const float var = s2 * (1.0f / 128.0f) - mu * mu;
        const float rstd = rsqrtf(var + 1e-5f);
#pragma unroll
        for (int i = 0; i < 8; ++i) {
            const int d = el + 16 * i;
            y[(size_t)node * 128 + d] = (x[i] - mu) * rstd * gamma[d] + beta[d];
        }
    }
}

// ---------------- launcher ----------------
extern "C" void kernel_launch(void* const* d_in, const int* in_sizes, int n_in,
                              void* d_out, int out_size, void* d_ws, size_t ws_size,
                              hipStream_t stream) {
    const int*   eidx  = (const int*)d_in[0];
    const float* efeat = (const float*)d_in[1];
    const float* inQ   = (const float*)d_in[2];
    const float* inK   = (const float*)d_in[3];
    const float* inV   = (const float*)d_in[4];
    const float* WQ    = (const float*)d_in[5];
    const float* WK    = (const float*)d_in[6];
    const float* WV    = (const float*)d_in[7];
    const float* WE    = (const float*)d_in[8];
    const float* Wfc   = (const float*)d_in[9];
    const float* gamma = (const float*)d_in[10];
    const float* beta  = (const float*)d_in[11];

    float* y = (float*)d_out;
    float* attn_out = y + (size_t)NN * 128;   // 3,200,000

    // ws layout (bytes):
    //   Qh fp16 (25000x128):   6,400,000 @ 0
    //   Kh fp16:               6,400,000 @ 6,400,000
    //   Vb bf16:               6,400,000 @ 12,800,000
    //   Whi (5x16384):           163,840 @ 19,200,000
    //   Wlo (3x16384):            98,304 @ 19,363,840
    //   WEf fp16 (16384):         32,768 @ 19,462,144
    //   attn_csr f32:          6,400,000 @ 19,494,912
    //   tgt_csr int:           1,600,000 @ 25,894,912
    //   pack int4:             6,400,000 @ 27,494,912
    //   deg int:                 100,352 @ 33,894,912
    //   cnt int:                 100,352 @ 33,995,264
    //   base int (NN+1):         100,352 @ 34,095,616  -> total 34,195,968
    char* ws = (char*)d_ws;
    _Float16* Qh   = (_Float16*)ws;
    _Float16* Kh   = (_Float16*)(ws + 6400000);
    short* Vb      = (short*)(ws + 12800000);
    short* Whi     = (short*)(ws + 19200000);
    short* Wlo     = (short*)(ws + 19363840);
    _Float16* WEf  = (_Float16*)(ws + 19462144);
    float* attn_csr= (float*)(ws + 19494912);
    int*   tgt_csr = (int*)  (ws + 25894912);
    int4*  pack    = (int4*) (ws + 27494912);
    int*   deg     = (int*)  (ws + 33894912);
    int*   cnt     = (int*)  (ws + 33995264);
    int*   base    = (int*)  (ws + 34095616);

    hipMemsetAsync(deg, 0, 200704, stream);   // deg + cnt

    convert_hist_kernel<<<576 + (EN + 255) / 256, 256, 0, stream>>>(
        WQ, WK, WV, WE, Wfc, Whi, Wlo, WEf, eidx, deg);
    scan_kernel<<<1, 1024, 0, stream>>>(deg, base);
    scatter_kernel<<<(EN + 255) / 256, 256, 0, stream>>>(eidx, base, cnt, pack, tgt_csr);

    dim3 pg(391, 3);
    proj_all_kernel<<<pg, 256, 0, stream>>>(inQ, inK, inV, Whi, Wlo, Qh, Kh, Vb);

    edge_score_kernel<<<2048, 256, 0, stream>>>(pack, efeat, Qh, Kh, WEf,
                                                attn_out, attn_csr);

    node_kernel<<<(NN + 31) / 32, 512, 0, stream>>>(base, tgt_csr, attn_csr, Vb,
                                                    Whi + 4 * 16384, inQ, gamma, beta, y);
}

// Round 16
// 234.813 us; speedup vs baseline: 1.1414x; 1.0252x over previous
//
#include <hip/hip_runtime.h>
#include <hip/hip_bf16.h>
#include <cstdint>
#include <cstddef>

// Problem constants (B=1)
#define EN 400000   // edges
#define NN 25000    // nodes
// D=128, H=4, DK=DV=32

typedef __attribute__((ext_vector_type(8))) short bf16x8;
typedef __attribute__((ext_vector_type(4))) short bf16x4;
typedef __attribute__((ext_vector_type(4))) float f32x4;
typedef __attribute__((ext_vector_type(4))) _Float16 f16x4;
typedef __attribute__((ext_vector_type(8))) _Float16 f16x8;

__device__ __forceinline__ short f2bf(float f) {
    unsigned int u = __float_as_uint(f);
    u = (u + 0x7fffu + ((u >> 16) & 1u)) >> 16;   // RNE
    return (short)u;
}
__device__ __forceinline__ float bf2f(short s) {
    return __uint_as_float(((unsigned int)(unsigned short)s) << 16);
}

// Identity ds_bpermute: result is DS-defined, so the compiler cannot rematerialize
// it from the original global load -> weight fragments stay register-resident.
__device__ __forceinline__ f16x8 pin8h(f16x8 v) {
    union { f16x8 s; int i[4]; } u; u.s = v;
    const int a = (threadIdx.x & 63) << 2;
#pragma unroll
    for (int k = 0; k < 4; ++k) u.i[k] = __builtin_amdgcn_ds_bpermute(a, u.i[k]);
    return u.s;
}

// ---------------- K0: weights -> fp16 (WQ,WK,WV,WE) + bf16 (Wfc) + degree histogram ---
__global__ __launch_bounds__(256) void convert_hist_kernel(
    const float* __restrict__ w0, const float* __restrict__ w1,
    const float* __restrict__ w2, const float* __restrict__ w3,
    const float* __restrict__ w4, _Float16* __restrict__ wf,
    short* __restrict__ wfc,
    const int* __restrict__ eidx, int* __restrict__ deg)
{
    if (blockIdx.x < 320) {
        int i = blockIdx.x * 256 + threadIdx.x;      // 81920 threads
        int w = i >> 14, off = i & 16383;
        if (w < 4) {
            const float* src = (w == 0) ? w0 : (w == 1) ? w1 : (w == 2) ? w2 : w3;
            wf[i] = (_Float16)src[off];              // order: WQ, WK, WV, WE
        } else {
            wfc[off] = f2bf(w4[off]);
        }
    } else {
        int e = (blockIdx.x - 320) * 256 + threadIdx.x;
        if (e < EN) atomicAdd(&deg[eidx[e]], 1);
    }
}

// ---------------- CSR scan ----------------
__global__ __launch_bounds__(1024) void scan_kernel(
    const int* __restrict__ deg, int* __restrict__ base)
{
    __shared__ int part[1024];
    const int t = threadIdx.x;
    const int CH = 25;                       // 1024*25 = 25600 >= NN
    int loc[CH];
    int s = 0;
#pragma unroll
    for (int i = 0; i < CH; ++i) {
        int idx = t * CH + i;
        loc[i] = s;
        s += (idx < NN) ? deg[idx] : 0;
    }
    part[t] = s;
    __syncthreads();
    for (int d = 1; d < 1024; d <<= 1) {
        int v = (t >= d) ? part[t - d] : 0;
        __syncthreads();
        part[t] += v;
        __syncthreads();
    }
    int off = (t > 0) ? part[t - 1] : 0;
#pragma unroll
    for (int i = 0; i < CH; ++i) {
        int idx = t * CH + i;
        if (idx < NN) base[idx] = off + loc[i];
    }
    if (t == 1023) base[NN] = part[1023];
}

// writes pack[e] = {src, tgt, csr_pos, 0} and tgt_csr[csr_pos] = tgt
__global__ __launch_bounds__(256) void scatter_kernel(
    const int* __restrict__ eidx, const int* __restrict__ base,
    int* __restrict__ cnt, int4* __restrict__ pack, int* __restrict__ tgt_csr)
{
    int e = blockIdx.x * 256 + threadIdx.x;
    if (e < EN) {
        int s = eidx[e];
        int tg = eidx[EN + e];
        int p = base[s] + atomicAdd(&cnt[s], 1);
        pack[e] = make_int4(s, tg, p, 0);
        tgt_csr[p] = tg;
    }
}

// ---------------- K1: fused head-split projections, single-pass fp16 (Q, K, V) -------
// blockIdx.y: 0=Q, 1=K, 2=V — identical code path, different src/dst pointers.
// Wave hw = head hw: outdims [32hw, 32hw+32). 8 MFMAs/tile; weights pinned (32 regs).
__global__ __launch_bounds__(256, 4) void proj_all_kernel(
    const float* __restrict__ inQ, const float* __restrict__ inK,
    const float* __restrict__ inV, const _Float16* __restrict__ WfBase,
    _Float16* __restrict__ Qh, _Float16* __restrict__ Kh, _Float16* __restrict__ Vh)
{
    const int mode = blockIdx.y;
    const int lane = threadIdx.x & 63;
    const int hw = threadIdx.x >> 6;          // head / wave
    const int el = lane & 15;
    const int g  = lane >> 4;
    const int ntiles = (NN + 15) >> 4;

    const float* X = (mode == 0) ? inQ : (mode == 1) ? inK : inV;
    const _Float16* Wf = WfBase + mode * 16384;
    _Float16* P = (mode == 0) ? Qh : (mode == 1) ? Kh : Vh;

    f16x8 wf[2][4];
#pragma unroll
    for (int dtt = 0; dtt < 2; ++dtt)
#pragma unroll
        for (int kc = 0; kc < 4; ++kc)
            wf[dtt][kc] = pin8h(*(const f16x8*)(Wf + (hw * 32 + dtt * 16 + el) * 128 + kc * 32 + g * 8));

    for (int tile = blockIdx.x; tile < ntiles; tile += gridDim.x) {
        const int row = tile * 16 + el;
        const int rc = row < NN ? row : NN - 1;
        const float* xrow = X + (size_t)rc * 128;
        f32x4 acc0 = {}, acc1 = {};
#pragma unroll
        for (int kc = 0; kc < 4; ++kc) {
            const int kb = kc * 32 + g * 8;
            f32x4 x0 = *(const f32x4*)(xrow + kb);
            f32x4 x1 = *(const f32x4*)(xrow + kb + 4);
            f16x8 b;
#pragma unroll
            for (int j = 0; j < 4; ++j) { b[j] = (_Float16)x0[j]; b[4 + j] = (_Float16)x1[j]; }
            acc0 = __builtin_amdgcn_mfma_f32_16x16x32_f16(wf[0][kc], b, acc0, 0, 0, 0);
            acc1 = __builtin_amdgcn_mfma_f32_16x16x32_f16(wf[1][kc], b, acc1, 0, 0, 0);
        }
        if (row < NN) {
            f16x4 o0, o1;
#pragma unroll
            for (int j = 0; j < 4; ++j) {
                o0[j] = (_Float16)acc0[j];
                o1[j] = (_Float16)acc1[j];
            }
            *(f16x4*)(P + (size_t)row * 128 + hw * 32 + g * 4)      = o0;
            *(f16x4*)(P + (size_t)row * 128 + hw * 32 + 16 + g * 4) = o1;
        }
    }
}

// ---------------- K2a: single-pass fp16 Ef-GEMM + score + exp (R15, unchanged) --------
__global__ __launch_bounds__(256, 4) void edge_score_kernel(
    const int4* __restrict__ pack, const float* __restrict__ efeat,
    const _Float16* __restrict__ Qh, const _Float16* __restrict__ Kh,
    const _Float16* __restrict__ WEf,
    float* __restrict__ attn_out, float* __restrict__ attn_csr)
{
    __shared__ _Float16 lds_e[2][16][136];   // [buf][edge][dim], 8.7 KB total

    const int t    = threadIdx.x;
    const int lane = t & 63;
    const int hw   = t >> 6;              // head / wave
    const int el   = lane & 15;
    const int g    = lane >> 4;
    const int se   = t >> 4;              // staging: edge 0..15
    const int sd   = (t & 15) * 8;        // staging: dim
    const int NT   = EN / 16;

    // pinned fp16 weight fragments (32 regs)
    f16x8 wf[2][4];
#pragma unroll
    for (int dtt = 0; dtt < 2; ++dtt)
#pragma unroll
        for (int kc = 0; kc < 4; ++kc) {
            const int r = hw * 32 + dtt * 16 + el;
            const int c = kc * 32 + g * 8;
            wf[dtt][kc] = pin8h(*(const f16x8*)(WEf + r * 128 + c));
        }

    const int dbase = hw * 32 + g * 4;
    int tile = blockIdx.x;
    int4 pk = pack[tile * 16 + el];

    // prologue: synchronous stage tile0 -> LDS[0]
    {
        const float* p = efeat + ((size_t)tile * 16 + se) * 128 + sd;
        f32x4 a = *(const f32x4*)p;
        f32x4 b = *(const f32x4*)(p + 4);
        f16x8 h8;
#pragma unroll
        for (int j = 0; j < 4; ++j) {
            h8[j] = (_Float16)a[j];
            h8[4 + j] = (_Float16)b[j];
        }
        *(f16x8*)&lds_e[0][se][sd] = h8;
    }
    // preload tile1 data into registers (written to LDS at end of iteration 0)
    f32x4 eA, eB;
    int4 pk1;
    {
        const int t1 = tile + (int)gridDim.x;
        const int tl1 = (t1 < NT) ? t1 : tile;
        const float* np = efeat + ((size_t)tl1 * 16 + se) * 128 + sd;
        eA = *(const f32x4*)np;
        eB = *(const f32x4*)(np + 4);
        pk1 = pack[tl1 * 16 + el];
    }

    int buf = 0;
    while (true) {
        // A) fp16 gathers for CURRENT tile (consumed at E, after the MFMA phase)
        const _Float16* qrow = Qh + (size_t)pk.x * 128 + dbase;
        const _Float16* krow = Kh + (size_t)pk.y * 128 + dbase;
        f16x4 q0 = *(const f16x4*)(qrow);
        f16x4 q1 = *(const f16x4*)(qrow + 16);
        f16x4 k0 = *(const f16x4*)(krow);
        f16x4 k1 = *(const f16x4*)(krow + 16);

        // B) issue efeat + pack loads for tile i+2 (consumed NEXT iteration at H)
        const int next = tile + (int)gridDim.x;
        const bool has_next = next < NT;
        const int n2 = next + (int)gridDim.x;
        const int tl2 = (n2 < NT) ? n2 : tile;
        const float* np2 = efeat + ((size_t)tl2 * 16 + se) * 128 + sd;
        f32x4 eAn = *(const f32x4*)np2;
        f32x4 eBn = *(const f32x4*)(np2 + 4);
        int4 pk2 = pack[tl2 * 16 + el];

        // C) barrier: order LDS double-buffer only — do NOT drain vmcnt
        asm volatile("s_waitcnt lgkmcnt(0)" ::: "memory");
        __builtin_amdgcn_s_barrier();
        __builtin_amdgcn_sched_barrier(0);

        // D) MFMA phase from LDS (lgkmcnt only): 8 fp16 MFMAs
        __builtin_amdgcn_s_setprio(1);
        f32x4 acc0 = {}, acc1 = {};
#pragma unroll
        for (int kc = 0; kc < 4; ++kc) {
            const int kb = kc * 32 + g * 8;
            f16x8 be = *(const f16x8*)&lds_e[buf][el][kb];
            acc0 = __builtin_amdgcn_mfma_f32_16x16x32_f16(wf[0][kc], be, acc0, 0, 0, 0);
            acc1 = __builtin_amdgcn_mfma_f32_16x16x32_f16(wf[1][kc], be, acc1, 0, 0, 0);
        }
        __builtin_amdgcn_s_setprio(0);

        // E) combine (gathers have had the MFMA phase to land)
        float part = 0.f;
#pragma unroll
        for (int j = 0; j < 4; ++j) {
            part += (float)q0[j] * (float)k0[j] * acc0[j];
            part += (float)q1[j] * (float)k1[j] * acc1[j];
        }
        part += __shfl_xor(part, 16, 64);
        part += __shfl_xor(part, 32, 64);
        float sc = part * 0.17677669529663687f;     // 1/sqrt(32)
        sc = fminf(5.0f, fmaxf(-5.0f, sc));
        const float a = __expf(sc);

        const int edge = tile * 16 + el;
        if (g == 0) {
            attn_out[(size_t)hw * EN + edge] = a;          // coalesced 64B per wave
            attn_csr[(size_t)pk.z * 4 + hw] = a;           // scattered 4B
        }

        if (!has_next) break;

        // H) write tile i+1 into LDS[buf^1] from eA/eB (loaded a FULL iteration ago)
        {
            f16x8 h8;
#pragma unroll
            for (int j = 0; j < 4; ++j) {
                h8[j] = (_Float16)eA[j];
                h8[4 + j] = (_Float16)eB[j];
            }
            *(f16x8*)&lds_e[buf ^ 1][se][sd] = h8;
        }

        // rotate pipeline state
        tile = next;
        pk = pk1;  pk1 = pk2;
        eA = eAn;  eB = eBn;
        buf ^= 1;
    }
}

// ---------------- K2b: per-node gather-reduce + W_fc matvec + residual + LN ----------
// 512 threads = 32 nodes/block: one W_fc LDS copy amortized 2x. V is fp16 now.
__global__ __launch_bounds__(512) void node_kernel(
    const int* __restrict__ base, const int* __restrict__ tgt_csr,
    const float* __restrict__ attn_csr, const _Float16* __restrict__ Vh,
    const short* __restrict__ Wfcb, const float* __restrict__ inQ,
    const float* __restrict__ gamma, const float* __restrict__ beta,
    float* __restrict__ y)
{
    __shared__ short wlds[128 * 136];   // padded: stride 136 bf16
    __shared__ float alds[32 * 132];    // padded: stride 132 f32

    const int t = threadIdx.x;
    // stage W_fc: thread handles row r=t>>2, cols (t&3)*32..+31
    {
        const int r = t >> 2, colb = (t & 3) * 32;
#pragma unroll
        for (int c = 0; c < 4; ++c) {
            bf16x8 w = *(const bf16x8*)(Wfcb + r * 128 + colb + c * 8);
            *(bf16x8*)(&wlds[r * 136 + colb + c * 8]) = w;
        }
    }

    const int n_l = t >> 4;             // 0..31
    const int el  = t & 15;
    const int node = blockIdx.x * 32 + n_l;

    int b0 = 0, b1 = 0;
    if (node < NN) { b0 = base[node]; b1 = base[node + 1]; }
    float acc[8] = {};
    float csum = 0.f;
    const int h = el >> 2;

    int p = b0;
    for (; p + 8 <= b1; p += 8) {      // unroll x8 for memory-level parallelism
        int   tg[8];
        float aa[8];
        f16x8 vv[8];
#pragma unroll
        for (int u = 0; u < 8; ++u) tg[u] = tgt_csr[p + u];
#pragma unroll
        for (int u = 0; u < 8; ++u) aa[u] = attn_csr[(size_t)(p + u) * 4 + h];
#pragma unroll
        for (int u = 0; u < 8; ++u) vv[u] = *(const f16x8*)(Vh + (size_t)tg[u] * 128 + el * 8);
#pragma unroll
        for (int u = 0; u < 8; ++u) {
            csum += aa[u];
#pragma unroll
            for (int j = 0; j < 8; ++j) acc[j] += aa[u] * (float)vv[u][j];
        }
    }
    for (; p < b1; ++p) {
        const int tg = tgt_csr[p];
        const float a = attn_csr[(size_t)p * 4 + h];
        f16x8 v = *(const f16x8*)(Vh + (size_t)tg * 128 + el * 8);
        csum += a;
#pragma unroll
        for (int j = 0; j < 8; ++j) acc[j] += a * (float)v[j];
    }

    const float invc = 1.0f / (csum + 1e-8f);
#pragma unroll
    for (int j = 0; j < 8; ++j) alds[n_l * 132 + el * 8 + j] = acc[j] * invc;
    __syncthreads();

    float fc[8] = {};
#pragma unroll 4
    for (int k0 = 0; k0 < 128; k0 += 8) {
        float a8[8];
#pragma unroll
        for (int j = 0; j < 8; ++j) a8[j] = alds[n_l * 132 + k0 + j];
#pragma unroll
        for (int i = 0; i < 8; ++i) {
            const int d = el + 16 * i;
            bf16x8 w = *(const bf16x8*)(&wlds[d * 136 + k0]);
#pragma unroll
            for (int j = 0; j < 8; ++j) fc[i] += a8[j] * bf2f(w[j]);
        }
    }

    if (node < NN) {
        float x[8];
        float s = 0.f, s2 = 0.f;
#pragma unroll
        for (int i = 0; i < 8; ++i) {
            const int d = el + 16 * i;
            x[i] = fc[i] + inQ[(size_t)node * 128 + d];
            s += x[i]; s2 += x[i] * x[i];
        }
        s  += __shfl_xor(s, 1, 64);  s2 += __shfl_xor(s2, 1, 64);
        s  += __shfl_xor(s, 2, 64);  s2 += __shfl_xor(s2, 2, 64);
        s  += __shfl_xor(s, 4, 64);  s2 += __shfl_xor(s2, 4, 64);
        s  += __shfl_xor(s, 8, 64);  s2 += __shfl_xor(s2, 8, 64);
        const float mu = s * (1.0f / 128.0f);
        const float var = s2 * (1.0f / 128.0f) - mu * mu;
        const float rstd = rsqrtf(var + 1e-5f);
#pragma unroll
        for (int i = 0; i < 8; ++i) {
            const int d = el + 16 * i;
            y[(size_t)node * 128 + d] = (x[i] - mu) * rstd * gamma[d] + beta[d];
        }
    }
}

// ---------------- launcher ----------------
extern "C" void kernel_launch(void* const* d_in, const int* in_sizes, int n_in,
                              void* d_out, int out_size, void* d_ws, size_t ws_size,
                              hipStream_t stream) {
    const int*   eidx  = (const int*)d_in[0];
    const float* efeat = (const float*)d_in[1];
    const float* inQ   = (const float*)d_in[2];
    const float* inK   = (const float*)d_in[3];
    const float* inV   = (const float*)d_in[4];
    const float* WQ    = (const float*)d_in[5];
    const float* WK    = (const float*)d_in[6];
    const float* WV    = (const float*)d_in[7];
    const float* WE    = (const float*)d_in[8];
    const float* Wfc   = (const float*)d_in[9];
    const float* gamma = (const float*)d_in[10];
    const float* beta  = (const float*)d_in[11];

    float* y = (float*)d_out;
    float* attn_out = y + (size_t)NN * 128;   // 3,200,000

    // ws layout (bytes):
    //   Qh fp16 (25000x128):   6,400,000 @ 0
    //   Kh fp16:               6,400,000 @ 6,400,000
    //   Vh fp16:               6,400,000 @ 12,800,000
    //   Wf fp16 (4x16384):       131,072 @ 19,200,000   (WQ,WK,WV,WE)
    //   Wfcb bf16 (16384):        32,768 @ 19,331,072
    //   attn_csr f32:          6,400,000 @ 19,363,840
    //   tgt_csr int:           1,600,000 @ 25,763,840
    //   pack int4:             6,400,000 @ 27,363,840
    //   deg int:                 100,352 @ 33,763,840
    //   cnt int:                 100,352 @ 33,864,192
    //   base int (NN+1):         100,352 @ 33,964,544  -> total 34,064,896
    char* ws = (char*)d_ws;
    _Float16* Qh   = (_Float16*)ws;
    _Float16* Kh   = (_Float16*)(ws + 6400000);
    _Float16* Vh   = (_Float16*)(ws + 12800000);
    _Float16* Wf   = (_Float16*)(ws + 19200000);
    short* Wfcb    = (short*)(ws + 19331072);
    float* attn_csr= (float*)(ws + 19363840);
    int*   tgt_csr = (int*)  (ws + 25763840);
    int4*  pack    = (int4*) (ws + 27363840);
    int*   deg     = (int*)  (ws + 33763840);
    int*   cnt     = (int*)  (ws + 33864192);
    int*   base    = (int*)  (ws + 33964544);

    hipMemsetAsync(deg, 0, 200704, stream);   // deg + cnt

    convert_hist_kernel<<<320 + (EN + 255) / 256, 256, 0, stream>>>(
        WQ, WK, WV, WE, Wfc, Wf, Wfcb, eidx, deg);
    scan_kernel<<<1, 1024, 0, stream>>>(deg, base);
    scatter_kernel<<<(EN + 255) / 256, 256, 0, stream>>>(eidx, base, cnt, pack, tgt_csr);

    dim3 pg(391, 3);
    proj_all_kernel<<<pg, 256, 0, stream>>>(inQ, inK, inV, Wf, Qh, Kh, Vh);

    edge_score_kernel<<<2048, 256, 0, stream>>>(pack, efeat, Qh, Kh, Wf + 3 * 16384,
                                                attn_out, attn_csr);

    node_kernel<<<(NN + 31) / 32, 512, 0, stream>>>(base, tgt_csr, attn_csr, Vh,
                                                    Wfcb, inQ, gamma, beta, y);
}

// Round 17
// 233.522 us; speedup vs baseline: 1.1477x; 1.0055x over previous
//
#include <hip/hip_runtime.h>
#include <hip/hip_bf16.h>
#include <cstdint>
#include <cstddef>

// Problem constants (B=1)
#define EN 400000   // edges
#define NN 25000    // nodes
// D=128, H=4, DK=DV=32

typedef __attribute__((ext_vector_type(8))) short bf16x8;
typedef __attribute__((ext_vector_type(4))) short bf16x4;
typedef __attribute__((ext_vector_type(4))) float f32x4;
typedef __attribute__((ext_vector_type(4))) _Float16 f16x4;
typedef __attribute__((ext_vector_type(8))) _Float16 f16x8;

__device__ __forceinline__ short f2bf(float f) {
    unsigned int u = __float_as_uint(f);
    u = (u + 0x7fffu + ((u >> 16) & 1u)) >> 16;   // RNE
    return (short)u;
}
__device__ __forceinline__ float bf2f(short s) {
    return __uint_as_float(((unsigned int)(unsigned short)s) << 16);
}

// Identity ds_bpermute: result is DS-defined, so the compiler cannot rematerialize
// it from the original global load -> weight fragments stay register-resident.
__device__ __forceinline__ f16x8 pin8h(f16x8 v) {
    union { f16x8 s; int i[4]; } u; u.s = v;
    const int a = (threadIdx.x & 63) << 2;
#pragma unroll
    for (int k = 0; k < 4; ++k) u.i[k] = __builtin_amdgcn_ds_bpermute(a, u.i[k]);
    return u.s;
}

// ---------------- K0: weights -> fp16 (WQ,WK,WV,WE) + bf16 (Wfc) + degree histogram ---
__global__ __launch_bounds__(256) void convert_hist_kernel(
    const float* __restrict__ w0, const float* __restrict__ w1,
    const float* __restrict__ w2, const float* __restrict__ w3,
    const float* __restrict__ w4, _Float16* __restrict__ wf,
    short* __restrict__ wfc,
    const int* __restrict__ eidx, int* __restrict__ deg)
{
    if (blockIdx.x < 320) {
        int i = blockIdx.x * 256 + threadIdx.x;      // 81920 threads
        int w = i >> 14, off = i & 16383;
        if (w < 4) {
            const float* src = (w == 0) ? w0 : (w == 1) ? w1 : (w == 2) ? w2 : w3;
            wf[i] = (_Float16)src[off];              // order: WQ, WK, WV, WE
        } else {
            wfc[off] = f2bf(w4[off]);
        }
    } else {
        int e = (blockIdx.x - 320) * 256 + threadIdx.x;
        if (e < EN) atomicAdd(&deg[eidx[e]], 1);
    }
}

// ---------------- CSR scan ----------------
__global__ __launch_bounds__(1024) void scan_kernel(
    const int* __restrict__ deg, int* __restrict__ base)
{
    __shared__ int part[1024];
    const int t = threadIdx.x;
    const int CH = 25;                       // 1024*25 = 25600 >= NN
    int loc[CH];
    int s = 0;
#pragma unroll
    for (int i = 0; i < CH; ++i) {
        int idx = t * CH + i;
        loc[i] = s;
        s += (idx < NN) ? deg[idx] : 0;
    }
    part[t] = s;
    __syncthreads();
    for (int d = 1; d < 1024; d <<= 1) {
        int v = (t >= d) ? part[t - d] : 0;
        __syncthreads();
        part[t] += v;
        __syncthreads();
    }
    int off = (t > 0) ? part[t - 1] : 0;
#pragma unroll
    for (int i = 0; i < CH; ++i) {
        int idx = t * CH + i;
        if (idx < NN) base[idx] = off + loc[i];
    }
    if (t == 1023) base[NN] = part[1023];
}

// writes pack[e] = {src, tgt, csr_pos, 0} and tgt_csr[csr_pos] = tgt
__global__ __launch_bounds__(256) void scatter_kernel(
    const int* __restrict__ eidx, const int* __restrict__ base,
    int* __restrict__ cnt, int4* __restrict__ pack, int* __restrict__ tgt_csr)
{
    int e = blockIdx.x * 256 + threadIdx.x;
    if (e < EN) {
        int s = eidx[e];
        int tg = eidx[EN + e];
        int p = base[s] + atomicAdd(&cnt[s], 1);
        pack[e] = make_int4(s, tg, p, 0);
        tgt_csr[p] = tg;
    }
}

// ---------------- K1: fused head-split projections, single-pass fp16 (Q, K, V) -------
// blockIdx.y: 0=Q, 1=K, 2=V — identical code path, different src/dst pointers.
__global__ __launch_bounds__(256, 4) void proj_all_kernel(
    const float* __restrict__ inQ, const float* __restrict__ inK,
    const float* __restrict__ inV, const _Float16* __restrict__ WfBase,
    _Float16* __restrict__ Qh, _Float16* __restrict__ Kh, _Float16* __restrict__ Vh)
{
    const int mode = blockIdx.y;
    const int lane = threadIdx.x & 63;
    const int hw = threadIdx.x >> 6;          // head / wave
    const int el = lane & 15;
    const int g  = lane >> 4;
    const int ntiles = (NN + 15) >> 4;

    const float* X = (mode == 0) ? inQ : (mode == 1) ? inK : inV;
    const _Float16* Wf = WfBase + mode * 16384;
    _Float16* P = (mode == 0) ? Qh : (mode == 1) ? Kh : Vh;

    f16x8 wf[2][4];
#pragma unroll
    for (int dtt = 0; dtt < 2; ++dtt)
#pragma unroll
        for (int kc = 0; kc < 4; ++kc)
            wf[dtt][kc] = pin8h(*(const f16x8*)(Wf + (hw * 32 + dtt * 16 + el) * 128 + kc * 32 + g * 8));

    for (int tile = blockIdx.x; tile < ntiles; tile += gridDim.x) {
        const int row = tile * 16 + el;
        const int rc = row < NN ? row : NN - 1;
        const float* xrow = X + (size_t)rc * 128;
        f32x4 acc0 = {}, acc1 = {};
#pragma unroll
        for (int kc = 0; kc < 4; ++kc) {
            const int kb = kc * 32 + g * 8;
            f32x4 x0 = *(const f32x4*)(xrow + kb);
            f32x4 x1 = *(const f32x4*)(xrow + kb + 4);
            f16x8 b;
#pragma unroll
            for (int j = 0; j < 4; ++j) { b[j] = (_Float16)x0[j]; b[4 + j] = (_Float16)x1[j]; }
            acc0 = __builtin_amdgcn_mfma_f32_16x16x32_f16(wf[0][kc], b, acc0, 0, 0, 0);
            acc1 = __builtin_amdgcn_mfma_f32_16x16x32_f16(wf[1][kc], b, acc1, 0, 0, 0);
        }
        if (row < NN) {
            f16x4 o0, o1;
#pragma unroll
            for (int j = 0; j < 4; ++j) {
                o0[j] = (_Float16)acc0[j];
                o1[j] = (_Float16)acc1[j];
            }
            *(f16x4*)(P + (size_t)row * 128 + hw * 32 + g * 4)      = o0;
            *(f16x4*)(P + (size_t)row * 128 + hw * 32 + 16 + g * 4) = o1;
        }
    }
}

// ---------------- K2a: 8-wave / 32-edge fp16 Ef-GEMM + score + exp ----------------
// 512 threads = 8 waves = 4 heads x 2 edge-subtiles sharing one 32-edge efeat tile in
// LDS. Per-wave work/registers identical to the R15 4-wave version — but barrier and
// staging amortize over 2x edges and waves/CU rises ~9 -> ~24 (latency hiding via TLP).
// Write-late staging + counted-vmcnt barrier retained.
__global__ __launch_bounds__(512, 2) void edge_score_kernel(
    const int4* __restrict__ pack, const float* __restrict__ efeat,
    const _Float16* __restrict__ Qh, const _Float16* __restrict__ Kh,
    const _Float16* __restrict__ WEf,
    float* __restrict__ attn_out, float* __restrict__ attn_csr)
{
    __shared__ _Float16 lds_e[2][32][136];   // [buf][edge][dim], 17.4 KB

    const int t    = threadIdx.x;
    const int lane = t & 63;
    const int w    = t >> 6;              // wave 0..7
    const int hw   = w & 3;               // head
    const int sub  = w >> 2;              // edge subtile 0/1
    const int el   = lane & 15;
    const int g    = lane >> 4;
    const int se   = t >> 4;              // staging: edge 0..31
    const int sd   = (t & 15) * 8;        // staging: dim
    const int NT   = EN / 32;             // 12500

    // pinned fp16 weight fragments (32 regs)
    f16x8 wf[2][4];
#pragma unroll
    for (int dtt = 0; dtt < 2; ++dtt)
#pragma unroll
        for (int kc = 0; kc < 4; ++kc) {
            const int r = hw * 32 + dtt * 16 + el;
            const int c = kc * 32 + g * 8;
            wf[dtt][kc] = pin8h(*(const f16x8*)(WEf + r * 128 + c));
        }

    const int dbase = hw * 32 + g * 4;
    int tile = blockIdx.x;
    int4 pk = pack[(size_t)tile * 32 + sub * 16 + el];

    // prologue: synchronous stage tile0 -> LDS[0]
    {
        const float* p = efeat + ((size_t)tile * 32 + se) * 128 + sd;
        f32x4 a = *(const f32x4*)p;
        f32x4 b = *(const f32x4*)(p + 4);
        f16x8 h8;
#pragma unroll
        for (int j = 0; j < 4; ++j) {
            h8[j] = (_Float16)a[j];
            h8[4 + j] = (_Float16)b[j];
        }
        *(f16x8*)&lds_e[0][se][sd] = h8;
    }
    // preload tile1 data into registers (written to LDS at end of iteration 0)
    f32x4 eA, eB;
    int4 pk1;
    {
        const int t1 = tile + (int)gridDim.x;
        const int tl1 = (t1 < NT) ? t1 : tile;
        const float* np = efeat + ((size_t)tl1 * 32 + se) * 128 + sd;
        eA = *(const f32x4*)np;
        eB = *(const f32x4*)(np + 4);
        pk1 = pack[(size_t)tl1 * 32 + sub * 16 + el];
    }

    int buf = 0;
    while (true) {
        // A) fp16 gathers for CURRENT tile (consumed at E, after the MFMA phase)
        const _Float16* qrow = Qh + (size_t)pk.x * 128 + dbase;
        const _Float16* krow = Kh + (size_t)pk.y * 128 + dbase;
        f16x4 q0 = *(const f16x4*)(qrow);
        f16x4 q1 = *(const f16x4*)(qrow + 16);
        f16x4 k0 = *(const f16x4*)(krow);
        f16x4 k1 = *(const f16x4*)(krow + 16);

        // B) issue efeat + pack loads for tile i+2 (consumed NEXT iteration at H)
        const int next = tile + (int)gridDim.x;
        const bool has_next = next < NT;
        const int n2 = next + (int)gridDim.x;
        const int tl2 = (n2 < NT) ? n2 : tile;
        const float* np2 = efeat + ((size_t)tl2 * 32 + se) * 128 + sd;
        f32x4 eAn = *(const f32x4*)np2;
        f32x4 eBn = *(const f32x4*)(np2 + 4);
        int4 pk2 = pack[(size_t)tl2 * 32 + sub * 16 + el];

        // C) barrier: order LDS double-buffer only — do NOT drain vmcnt
        asm volatile("s_waitcnt lgkmcnt(0)" ::: "memory");
        __builtin_amdgcn_s_barrier();
        __builtin_amdgcn_sched_barrier(0);

        // D) MFMA phase from LDS (lgkmcnt only): 8 fp16 MFMAs on this wave's subtile
        __builtin_amdgcn_s_setprio(1);
        f32x4 acc0 = {}, acc1 = {};
#pragma unroll
        for (int kc = 0; kc < 4; ++kc) {
            const int kb = kc * 32 + g * 8;
            f16x8 be = *(const f16x8*)&lds_e[buf][sub * 16 + el][kb];
            acc0 = __builtin_amdgcn_mfma_f32_16x16x32_f16(wf[0][kc], be, acc0, 0, 0, 0);
            acc1 = __builtin_amdgcn_mfma_f32_16x16x32_f16(wf[1][kc], be, acc1, 0, 0, 0);
        }
        __builtin_amdgcn_s_setprio(0);

        // E) combine (gathers have had the MFMA phase to land)
        float part = 0.f;
#pragma unroll
        for (int j = 0; j < 4; ++j) {
            part += (float)q0[j] * (float)k0[j] * acc0[j];
            part += (float)q1[j] * (float)k1[j] * acc1[j];
        }
        part += __shfl_xor(part, 16, 64);
        part += __shfl_xor(part, 32, 64);
        float sc = part * 0.17677669529663687f;     // 1/sqrt(32)
        sc = fminf(5.0f, fmaxf(-5.0f, sc));
        const float a = __expf(sc);

        const int edge = tile * 32 + sub * 16 + el;
        if (g == 0) {
            attn_out[(size_t)hw * EN + edge] = a;          // coalesced 64B per wave
            attn_csr[(size_t)pk.z * 4 + hw] = a;           // scattered 4B
        }

        if (!has_next) break;

        // H) write tile i+1 into LDS[buf^1] from eA/eB (loaded a FULL iteration ago)
        {
            f16x8 h8;
#pragma unroll
            for (int j = 0; j < 4; ++j) {
                h8[j] = (_Float16)eA[j];
                h8[4 + j] = (_Float16)eB[j];
            }
            *(f16x8*)&lds_e[buf ^ 1][se][sd] = h8;
        }

        // rotate pipeline state
        tile = next;
        pk = pk1;  pk1 = pk2;
        eA = eAn;  eB = eBn;
        buf ^= 1;
    }
}

// ---------------- K2b: per-node gather-reduce + W_fc matvec + residual + LN ----------
// 512 threads = 32 nodes/block: one W_fc LDS copy amortized 2x. V is fp16.
__global__ __launch_bounds__(512) void node_kernel(
    const int* __restrict__ base, const int* __restrict__ tgt_csr,
    const float* __restrict__ attn_csr, const _Float16* __restrict__ Vh,
    const short* __restrict__ Wfcb, const float* __restrict__ inQ,
    const float* __restrict__ gamma, const float* __restrict__ beta,
    float* __restrict__ y)
{
    __shared__ short wlds[128 * 136];   // padded: stride 136 bf16
    __shared__ float alds[32 * 132];    // padded: stride 132 f32

    const int t = threadIdx.x;
    // stage W_fc: thread handles row r=t>>2, cols (t&3)*32..+31
    {
        const int r = t >> 2, colb = (t & 3) * 32;
#pragma unroll
        for (int c = 0; c < 4; ++c) {
            bf16x8 w = *(const bf16x8*)(Wfcb + r * 128 + colb + c * 8);
            *(bf16x8*)(&wlds[r * 136 + colb + c * 8]) = w;
        }
    }

    const int n_l = t >> 4;             // 0..31
    const int el  = t & 15;
    const int node = blockIdx.x * 32 + n_l;

    int b0 = 0, b1 = 0;
    if (node < NN) { b0 = base[node]; b1 = base[node + 1]; }
    float acc[8] = {};
    float csum = 0.f;
    const int h = el >> 2;

    int p = b0;
    for (; p + 8 <= b1; p += 8) {      // unroll x8 for memory-level parallelism
        int   tg[8];
        float aa[8];
        f16x8 vv[8];
#pragma unroll
        for (int u = 0; u < 8; ++u) tg[u] = tgt_csr[p + u];
#pragma unroll
        for (int u = 0; u < 8; ++u) aa[u] = attn_csr[(size_t)(p + u) * 4 + h];
#pragma unroll
        for (int u = 0; u < 8; ++u) vv[u] = *(const f16x8*)(Vh + (size_t)tg[u] * 128 + el * 8);
#pragma unroll
        for (int u = 0; u < 8; ++u) {
            csum += aa[u];
#pragma unroll
            for (int j = 0; j < 8; ++j) acc[j] += aa[u] * (float)vv[u][j];
        }
    }
    for (; p < b1; ++p) {
        const int tg = tgt_csr[p];
        const float a = attn_csr[(size_t)p * 4 + h];
        f16x8 v = *(const f16x8*)(Vh + (size_t)tg * 128 + el * 8);
        csum += a;
#pragma unroll
        for (int j = 0; j < 8; ++j) acc[j] += a * (float)v[j];
    }

    const float invc = 1.0f / (csum + 1e-8f);
#pragma unroll
    for (int j = 0; j < 8; ++j) alds[n_l * 132 + el * 8 + j] = acc[j] * invc;
    __syncthreads();

    float fc[8] = {};
#pragma unroll 4
    for (int k0 = 0; k0 < 128; k0 += 8) {
        float a8[8];
#pragma unroll
        for (int j = 0; j < 8; ++j) a8[j] = alds[n_l * 132 + k0 + j];
#pragma unroll
        for (int i = 0; i < 8; ++i) {
            const int d = el + 16 * i;
            bf16x8 w = *(const bf16x8*)(&wlds[d * 136 + k0]);
#pragma unroll
            for (int j = 0; j < 8; ++j) fc[i] += a8[j] * bf2f(w[j]);
        }
    }

    if (node < NN) {
        float x[8];
        float s = 0.f, s2 = 0.f;
#pragma unroll
        for (int i = 0; i < 8; ++i) {
            const int d = el + 16 * i;
            x[i] = fc[i] + inQ[(size_t)node * 128 + d];
            s += x[i]; s2 += x[i] * x[i];
        }
        s  += __shfl_xor(s, 1, 64);  s2 += __shfl_xor(s2, 1, 64);
        s  += __shfl_xor(s, 2, 64);  s2 += __shfl_xor(s2, 2, 64);
        s  += __shfl_xor(s, 4, 64);  s2 += __shfl_xor(s2, 4, 64);
        s  += __shfl_xor(s, 8, 64);  s2 += __shfl_xor(s2, 8, 64);
        const float mu = s * (1.0f / 128.0f);
        const float var = s2 * (1.0f / 128.0f) - mu * mu;
        const float rstd = rsqrtf(var + 1e-5f);
#pragma unroll
        for (int i = 0; i < 8; ++i) {
            const int d = el + 16 * i;
            y[(size_t)node * 128 + d] = (x[i] - mu) * rstd * gamma[d] + beta[d];
        }
    }
}

// ---------------- launcher ----------------
extern "C" void kernel_launch(void* const* d_in, const int* in_sizes, int n_in,
                              void* d_out, int out_size, void* d_ws, size_t ws_size,
                              hipStream_t stream) {
    const int*   eidx  = (const int*)d_in[0];
    const float* efeat = (const float*)d_in[1];
    const float* inQ   = (const float*)d_in[2];
    const float* inK   = (const float*)d_in[3];
    const float* inV   = (const float*)d_in[4];
    const float* WQ    = (const float*)d_in[5];
    const float* WK    = (const float*)d_in[6];
    const float* WV    = (const float*)d_in[7];
    const float* WE    = (const float*)d_in[8];
    const float* Wfc   = (const float*)d_in[9];
    const float* gamma = (const float*)d_in[10];
    const float* beta  = (const float*)d_in[11];

    float* y = (float*)d_out;
    float* attn_out = y + (size_t)NN * 128;   // 3,200,000

    // ws layout (bytes): same as R16
    char* ws = (char*)d_ws;
    _Float16* Qh   = (_Float16*)ws;
    _Float16* Kh   = (_Float16*)(ws + 6400000);
    _Float16* Vh   = (_Float16*)(ws + 12800000);
    _Float16* Wf   = (_Float16*)(ws + 19200000);
    short* Wfcb    = (short*)(ws + 19331072);
    float* attn_csr= (float*)(ws + 19363840);
    int*   tgt_csr = (int*)  (ws + 25763840);
    int4*  pack    = (int4*) (ws + 27363840);
    int*   deg     = (int*)  (ws + 33763840);
    int*   cnt     = (int*)  (ws + 33864192);
    int*   base    = (int*)  (ws + 33964544);

    hipMemsetAsync(deg, 0, 200704, stream);   // deg + cnt

    convert_hist_kernel<<<320 + (EN + 255) / 256, 256, 0, stream>>>(
        WQ, WK, WV, WE, Wfc, Wf, Wfcb, eidx, deg);
    scan_kernel<<<1, 1024, 0, stream>>>(deg, base);
    scatter_kernel<<<(EN + 255) / 256, 256, 0, stream>>>(eidx, base, cnt, pack, tgt_csr);

    dim3 pg(391, 3);
    proj_all_kernel<<<pg, 256, 0, stream>>>(inQ, inK, inV, Wf, Qh, Kh, Vh);

    edge_score_kernel<<<768, 512, 0, stream>>>(pack, efeat, Qh, Kh, Wf + 3 * 16384,
                                               attn_out, attn_csr);

    node_kernel<<<(NN + 31) / 32, 512, 0, stream>>>(base, tgt_csr, attn_csr, Vh,
                                                    Wfcb, inQ, gamma, beta, y);
}

// Round 18
// 219.225 us; speedup vs baseline: 1.2226x; 1.0652x over previous
//
#include <hip/hip_runtime.h>
#include <hip/hip_bf16.h>
#include <cstdint>
#include <cstddef>

// Problem constants (B=1)
#define EN 400000   // edges
#define NN 25000    // nodes
// D=128, H=4, DK=DV=32

typedef __attribute__((ext_vector_type(8))) short bf16x8;
typedef __attribute__((ext_vector_type(4))) short bf16x4;
typedef __attribute__((ext_vector_type(4))) float f32x4;
typedef __attribute__((ext_vector_type(4))) _Float16 f16x4;
typedef __attribute__((ext_vector_type(8))) _Float16 f16x8;

__device__ __forceinline__ short f2bf(float f) {
    unsigned int u = __float_as_uint(f);
    u = (u + 0x7fffu + ((u >> 16) & 1u)) >> 16;   // RNE
    return (short)u;
}
__device__ __forceinline__ float bf2f(short s) {
    return __uint_as_float(((unsigned int)(unsigned short)s) << 16);
}

// Identity ds_bpermute: result is DS-defined, so the compiler cannot rematerialize
// it from the original global load -> weight fragments stay register-resident.
__device__ __forceinline__ f16x8 pin8h(f16x8 v) {
    union { f16x8 s; int i[4]; } u; u.s = v;
    const int a = (threadIdx.x & 63) << 2;
#pragma unroll
    for (int k = 0; k < 4; ++k) u.i[k] = __builtin_amdgcn_ds_bpermute(a, u.i[k]);
    return u.s;
}

// ---------------- K0: weights -> fp16 (WQ,WK,WV,WE) + bf16 (Wfc) + degree histogram ---
__global__ __launch_bounds__(256) void convert_hist_kernel(
    const float* __restrict__ w0, const float* __restrict__ w1,
    const float* __restrict__ w2, const float* __restrict__ w3,
    const float* __restrict__ w4, _Float16* __restrict__ wf,
    short* __restrict__ wfc,
    const int* __restrict__ eidx, int* __restrict__ deg)
{
    if (blockIdx.x < 320) {
        int i = blockIdx.x * 256 + threadIdx.x;      // 81920 threads
        int w = i >> 14, off = i & 16383;
        if (w < 4) {
            const float* src = (w == 0) ? w0 : (w == 1) ? w1 : (w == 2) ? w2 : w3;
            wf[i] = (_Float16)src[off];              // order: WQ, WK, WV, WE
        } else {
            wfc[off] = f2bf(w4[off]);
        }
    } else {
        int e = (blockIdx.x - 320) * 256 + threadIdx.x;
        if (e < EN) atomicAdd(&deg[eidx[e]], 1);
    }
}

// ---------------- CSR scan ----------------
__global__ __launch_bounds__(1024) void scan_kernel(
    const int* __restrict__ deg, int* __restrict__ base)
{
    __shared__ int part[1024];
    const int t = threadIdx.x;
    const int CH = 25;                       // 1024*25 = 25600 >= NN
    int loc[CH];
    int s = 0;
#pragma unroll
    for (int i = 0; i < CH; ++i) {
        int idx = t * CH + i;
        loc[i] = s;
        s += (idx < NN) ? deg[idx] : 0;
    }
    part[t] = s;
    __syncthreads();
    for (int d = 1; d < 1024; d <<= 1) {
        int v = (t >= d) ? part[t - d] : 0;
        __syncthreads();
        part[t] += v;
        __syncthreads();
    }
    int off = (t > 0) ? part[t - 1] : 0;
#pragma unroll
    for (int i = 0; i < CH; ++i) {
        int idx = t * CH + i;
        if (idx < NN) base[idx] = off + loc[i];
    }
    if (t == 1023) base[NN] = part[1023];
}

// writes pack[e] = {src, tgt, csr_pos, 0} and tgt_csr[csr_pos] = tgt
__global__ __launch_bounds__(256) void scatter_kernel(
    const int* __restrict__ eidx, const int* __restrict__ base,
    int* __restrict__ cnt, int4* __restrict__ pack, int* __restrict__ tgt_csr)
{
    int e = blockIdx.x * 256 + threadIdx.x;
    if (e < EN) {
        int s = eidx[e];
        int tg = eidx[EN + e];
        int p = base[s] + atomicAdd(&cnt[s], 1);
        pack[e] = make_int4(s, tg, p, 0);
        tgt_csr[p] = tg;
    }
}

// ---------------- K1: fused head-split projections, single-pass fp16 (Q, K, V) -------
// blockIdx.y: 0=Q, 1=K, 2=V. PERMUTED A-rows: lane el's A fragment holds W row
// hw*32 + (el>>2)*8 + dtt*4 + (el&3), so lane (el,g) accumulates dims
// hw*32 + g*8 + dtt*4 + j  -> output is ONE contiguous f16x8 (16B) store per lane.
__global__ __launch_bounds__(256, 4) void proj_all_kernel(
    const float* __restrict__ inQ, const float* __restrict__ inK,
    const float* __restrict__ inV, const _Float16* __restrict__ WfBase,
    _Float16* __restrict__ Qh, _Float16* __restrict__ Kh, _Float16* __restrict__ Vh)
{
    const int mode = blockIdx.y;
    const int lane = threadIdx.x & 63;
    const int hw = threadIdx.x >> 6;          // head / wave
    const int el = lane & 15;
    const int g  = lane >> 4;
    const int ntiles = (NN + 15) >> 4;

    const float* X = (mode == 0) ? inQ : (mode == 1) ? inK : inV;
    const _Float16* Wf = WfBase + mode * 16384;
    _Float16* P = (mode == 0) ? Qh : (mode == 1) ? Kh : Vh;

    f16x8 wf[2][4];
#pragma unroll
    for (int dtt = 0; dtt < 2; ++dtt)
#pragma unroll
        for (int kc = 0; kc < 4; ++kc) {
            const int r = hw * 32 + ((el >> 2) * 8) + dtt * 4 + (el & 3);  // permuted
            wf[dtt][kc] = pin8h(*(const f16x8*)(Wf + r * 128 + kc * 32 + g * 8));
        }

    for (int tile = blockIdx.x; tile < ntiles; tile += gridDim.x) {
        const int row = tile * 16 + el;
        const int rc = row < NN ? row : NN - 1;
        const float* xrow = X + (size_t)rc * 128;
        f32x4 acc0 = {}, acc1 = {};
#pragma unroll
        for (int kc = 0; kc < 4; ++kc) {
            const int kb = kc * 32 + g * 8;
            f32x4 x0 = *(const f32x4*)(xrow + kb);
            f32x4 x1 = *(const f32x4*)(xrow + kb + 4);
            f16x8 b;
#pragma unroll
            for (int j = 0; j < 4; ++j) { b[j] = (_Float16)x0[j]; b[4 + j] = (_Float16)x1[j]; }
            acc0 = __builtin_amdgcn_mfma_f32_16x16x32_f16(wf[0][kc], b, acc0, 0, 0, 0);
            acc1 = __builtin_amdgcn_mfma_f32_16x16x32_f16(wf[1][kc], b, acc1, 0, 0, 0);
        }
        if (row < NN) {
            // lane (el,g): acc0[j] = dim hw*32+g*8+j, acc1[j] = dim hw*32+g*8+4+j
            f16x8 o;
#pragma unroll
            for (int j = 0; j < 4; ++j) {
                o[j]     = (_Float16)acc0[j];
                o[4 + j] = (_Float16)acc1[j];
            }
            *(f16x8*)(P + (size_t)row * 128 + hw * 32 + g * 8) = o;
        }
    }
}

// ---------------- K2a: 8-wave / 32-edge fp16 Ef-GEMM + score + exp ----------------
// Permuted A-rows (see K1): lane (el,g) holds score-dims hw*32+g*8..+8, so the Q/K
// gathers are ONE contiguous f16x8 (16B) load each — 2 scattered VMEM instrs per
// wave-iter instead of 4, and 4 g-lanes cover a full 64B line (requests halved).
// Write-late staging + counted-vmcnt barrier retained.
__global__ __launch_bounds__(512, 2) void edge_score_kernel(
    const int4* __restrict__ pack, const float* __restrict__ efeat,
    const _Float16* __restrict__ Qh, const _Float16* __restrict__ Kh,
    const _Float16* __restrict__ WEf,
    float* __restrict__ attn_out, float* __restrict__ attn_csr)
{
    __shared__ _Float16 lds_e[2][32][136];   // [buf][edge][dim], 17.4 KB

    const int t    = threadIdx.x;
    const int lane = t & 63;
    const int w    = t >> 6;              // wave 0..7
    const int hw   = w & 3;               // head
    const int sub  = w >> 2;              // edge subtile 0/1
    const int el   = lane & 15;
    const int g    = lane >> 4;
    const int se   = t >> 4;              // staging: edge 0..31
    const int sd   = (t & 15) * 8;        // staging: dim
    const int NT   = EN / 32;             // 12500

    // pinned fp16 weight fragments, PERMUTED rows (32 regs)
    f16x8 wf[2][4];
#pragma unroll
    for (int dtt = 0; dtt < 2; ++dtt)
#pragma unroll
        for (int kc = 0; kc < 4; ++kc) {
            const int r = hw * 32 + ((el >> 2) * 8) + dtt * 4 + (el & 3);  // permuted
            wf[dtt][kc] = pin8h(*(const f16x8*)(WEf + r * 128 + kc * 32 + g * 8));
        }

    const int dbase = hw * 32 + g * 8;
    int tile = blockIdx.x;
    int4 pk = pack[(size_t)tile * 32 + sub * 16 + el];

    // prologue: synchronous stage tile0 -> LDS[0]
    {
        const float* p = efeat + ((size_t)tile * 32 + se) * 128 + sd;
        f32x4 a = *(const f32x4*)p;
        f32x4 b = *(const f32x4*)(p + 4);
        f16x8 h8;
#pragma unroll
        for (int j = 0; j < 4; ++j) {
            h8[j] = (_Float16)a[j];
            h8[4 + j] = (_Float16)b[j];
        }
        *(f16x8*)&lds_e[0][se][sd] = h8;
    }
    // preload tile1 data into registers (written to LDS at end of iteration 0)
    f32x4 eA, eB;
    int4 pk1;
    {
        const int t1 = tile + (int)gridDim.x;
        const int tl1 = (t1 < NT) ? t1 : tile;
        const float* np = efeat + ((size_t)tl1 * 32 + se) * 128 + sd;
        eA = *(const f32x4*)np;
        eB = *(const f32x4*)(np + 4);
        pk1 = pack[(size_t)tl1 * 32 + sub * 16 + el];
    }

    int buf = 0;
    while (true) {
        // A) fp16 gathers for CURRENT tile — one 16B load per operand per lane
        f16x8 q16 = *(const f16x8*)(Qh + (size_t)pk.x * 128 + dbase);
        f16x8 k16 = *(const f16x8*)(Kh + (size_t)pk.y * 128 + dbase);

        // B) issue efeat + pack loads for tile i+2 (consumed NEXT iteration at H)
        const int next = tile + (int)gridDim.x;
        const bool has_next = next < NT;
        const int n2 = next + (int)gridDim.x;
        const int tl2 = (n2 < NT) ? n2 : tile;
        const float* np2 = efeat + ((size_t)tl2 * 32 + se) * 128 + sd;
        f32x4 eAn = *(const f32x4*)np2;
        f32x4 eBn = *(const f32x4*)(np2 + 4);
        int4 pk2 = pack[(size_t)tl2 * 32 + sub * 16 + el];

        // C) barrier: order LDS double-buffer only — do NOT drain vmcnt
        asm volatile("s_waitcnt lgkmcnt(0)" ::: "memory");
        __builtin_amdgcn_s_barrier();
        __builtin_amdgcn_sched_barrier(0);

        // D) MFMA phase from LDS (lgkmcnt only): 8 fp16 MFMAs on this wave's subtile
        __builtin_amdgcn_s_setprio(1);
        f32x4 acc0 = {}, acc1 = {};
#pragma unroll
        for (int kc = 0; kc < 4; ++kc) {
            const int kb = kc * 32 + g * 8;
            f16x8 be = *(const f16x8*)&lds_e[buf][sub * 16 + el][kb];
            acc0 = __builtin_amdgcn_mfma_f32_16x16x32_f16(wf[0][kc], be, acc0, 0, 0, 0);
            acc1 = __builtin_amdgcn_mfma_f32_16x16x32_f16(wf[1][kc], be, acc1, 0, 0, 0);
        }
        __builtin_amdgcn_s_setprio(0);

        // E) combine: lane covers dims dbase..dbase+8 (acc0 = +0..4, acc1 = +4..8)
        float part = 0.f;
#pragma unroll
        for (int j = 0; j < 4; ++j) {
            part += (float)q16[j]     * (float)k16[j]     * acc0[j];
            part += (float)q16[4 + j] * (float)k16[4 + j] * acc1[j];
        }
        part += __shfl_xor(part, 16, 64);
        part += __shfl_xor(part, 32, 64);
        float sc = part * 0.17677669529663687f;     // 1/sqrt(32)
        sc = fminf(5.0f, fmaxf(-5.0f, sc));
        const float a = __expf(sc);

        const int edge = tile * 32 + sub * 16 + el;
        if (g == 0) {
            attn_out[(size_t)hw * EN + edge] = a;          // coalesced 64B per wave
            attn_csr[(size_t)pk.z * 4 + hw] = a;           // scattered 4B
        }

        if (!has_next) break;

        // H) write tile i+1 into LDS[buf^1] from eA/eB (loaded a FULL iteration ago)
        {
            f16x8 h8;
#pragma unroll
            for (int j = 0; j < 4; ++j) {
                h8[j] = (_Float16)eA[j];
                h8[4 + j] = (_Float16)eB[j];
            }
            *(f16x8*)&lds_e[buf ^ 1][se][sd] = h8;
        }

        // rotate pipeline state
        tile = next;
        pk = pk1;  pk1 = pk2;
        eA = eAn;  eB = eBn;
        buf ^= 1;
    }
}

// ---------------- K2b: per-node gather-reduce + W_fc matvec + residual + LN ----------
// 512 threads = 32 nodes/block: one W_fc LDS copy amortized 2x. V is fp16.
__global__ __launch_bounds__(512) void node_kernel(
    const int* __restrict__ base, const int* __restrict__ tgt_csr,
    const float* __restrict__ attn_csr, const _Float16* __restrict__ Vh,
    const short* __restrict__ Wfcb, const float* __restrict__ inQ,
    const float* __restrict__ gamma, const float* __restrict__ beta,
    float* __restrict__ y)
{
    __shared__ short wlds[128 * 136];   // padded: stride 136 bf16
    __shared__ float alds[32 * 132];    // padded: stride 132 f32

    const int t = threadIdx.x;
    // stage W_fc: thread handles row r=t>>2, cols (t&3)*32..+31
    {
        const int r = t >> 2, colb = (t & 3) * 32;
#pragma unroll
        for (int c = 0; c < 4; ++c) {
            bf16x8 w = *(const bf16x8*)(Wfcb + r * 128 + colb + c * 8);
            *(bf16x8*)(&wlds[r * 136 + colb + c * 8]) = w;
        }
    }

    const int n_l = t >> 4;             // 0..31
    const int el  = t & 15;
    const int node = blockIdx.x * 32 + n_l;

    int b0 = 0, b1 = 0;
    if (node < NN) { b0 = base[node]; b1 = base[node + 1]; }
    float acc[8] = {};
    float csum = 0.f;
    const int h = el >> 2;

    int p = b0;
    for (; p + 8 <= b1; p += 8) {      // unroll x8 for memory-level parallelism
        int   tg[8];
        float aa[8];
        f16x8 vv[8];
#pragma unroll
        for (int u = 0; u < 8; ++u) tg[u] = tgt_csr[p + u];
#pragma unroll
        for (int u = 0; u < 8; ++u) aa[u] = attn_csr[(size_t)(p + u) * 4 + h];
#pragma unroll
        for (int u = 0; u < 8; ++u) vv[u] = *(const f16x8*)(Vh + (size_t)tg[u] * 128 + el * 8);
#pragma unroll
        for (int u = 0; u < 8; ++u) {
            csum += aa[u];
#pragma unroll
            for (int j = 0; j < 8; ++j) acc[j] += aa[u] * (float)vv[u][j];
        }
    }
    for (; p < b1; ++p) {
        const int tg = tgt_csr[p];
        const float a = attn_csr[(size_t)p * 4 + h];
        f16x8 v = *(const f16x8*)(Vh + (size_t)tg * 128 + el * 8);
        csum += a;
#pragma unroll
        for (int j = 0; j < 8; ++j) acc[j] += a * (float)v[j];
    }

    const float invc = 1.0f / (csum + 1e-8f);
#pragma unroll
    for (int j = 0; j < 8; ++j) alds[n_l * 132 + el * 8 + j] = acc[j] * invc;
    __syncthreads();

    float fc[8] = {};
#pragma unroll 4
    for (int k0 = 0; k0 < 128; k0 += 8) {
        float a8[8];
#pragma unroll
        for (int j = 0; j < 8; ++j) a8[j] = alds[n_l * 132 + k0 + j];
#pragma unroll
        for (int i = 0; i < 8; ++i) {
            const int d = el + 16 * i;
            bf16x8 w = *(const bf16x8*)(&wlds[d * 136 + k0]);
#pragma unroll
            for (int j = 0; j < 8; ++j) fc[i] += a8[j] * bf2f(w[j]);
        }
    }

    if (node < NN) {
        float x[8];
        float s = 0.f, s2 = 0.f;
#pragma unroll
        for (int i = 0; i < 8; ++i) {
            const int d = el + 16 * i;
            x[i] = fc[i] + inQ[(size_t)node * 128 + d];
            s += x[i]; s2 += x[i] * x[i];
        }
        s  += __shfl_xor(s, 1, 64);  s2 += __shfl_xor(s2, 1, 64);
        s  += __shfl_xor(s, 2, 64);  s2 += __shfl_xor(s2, 2, 64);
        s  += __shfl_xor(s, 4, 64);  s2 += __shfl_xor(s2, 4, 64);
        s  += __shfl_xor(s, 8, 64);  s2 += __shfl_xor(s2, 8, 64);
        const float mu = s * (1.0f / 128.0f);
        const float var = s2 * (1.0f / 128.0f) - mu * mu;
        const float rstd = rsqrtf(var + 1e-5f);
#pragma unroll
        for (int i = 0; i < 8; ++i) {
            const int d = el + 16 * i;
            y[(size_t)node * 128 + d] = (x[i] - mu) * rstd * gamma[d] + beta[d];
        }
    }
}

// ---------------- launcher ----------------
extern "C" void kernel_launch(void* const* d_in, const int* in_sizes, int n_in,
                              void* d_out, int out_size, void* d_ws, size_t ws_size,
                              hipStream_t stream) {
    const int*   eidx  = (const int*)d_in[0];
    const float* efeat = (const float*)d_in[1];
    const float* inQ   = (const float*)d_in[2];
    const float* inK   = (const float*)d_in[3];
    const float* inV   = (const float*)d_in[4];
    const float* WQ    = (const float*)d_in[5];
    const float* WK    = (const float*)d_in[6];
    const float* WV    = (const float*)d_in[7];
    const float* WE    = (const float*)d_in[8];
    const float* Wfc   = (const float*)d_in[9];
    const float* gamma = (const float*)d_in[10];
    const float* beta  = (const float*)d_in[11];

    float* y = (float*)d_out;
    float* attn_out = y + (size_t)NN * 128;   // 3,200,000

    // ws layout (bytes): same as R16/R17
    char* ws = (char*)d_ws;
    _Float16* Qh   = (_Float16*)ws;
    _Float16* Kh   = (_Float16*)(ws + 6400000);
    _Float16* Vh   = (_Float16*)(ws + 12800000);
    _Float16* Wf   = (_Float16*)(ws + 19200000);
    short* Wfcb    = (short*)(ws + 19331072);
    float* attn_csr= (float*)(ws + 19363840);
    int*   tgt_csr = (int*)  (ws + 25763840);
    int4*  pack    = (int4*) (ws + 27363840);
    int*   deg     = (int*)  (ws + 33763840);
    int*   cnt     = (int*)  (ws + 33864192);
    int*   base    = (int*)  (ws + 33964544);

    hipMemsetAsync(deg, 0, 200704, stream);   // deg + cnt

    convert_hist_kernel<<<320 + (EN + 255) / 256, 256, 0, stream>>>(
        WQ, WK, WV, WE, Wfc, Wf, Wfcb, eidx, deg);
    scan_kernel<<<1, 1024, 0, stream>>>(deg, base);
    scatter_kernel<<<(EN + 255) / 256, 256, 0, stream>>>(eidx, base, cnt, pack, tgt_csr);

    dim3 pg(391, 3);
    proj_all_kernel<<<pg, 256, 0, stream>>>(inQ, inK, inV, Wf, Qh, Kh, Vh);

    edge_score_kernel<<<768, 512, 0, stream>>>(pack, efeat, Qh, Kh, Wf + 3 * 16384,
                                               attn_out, attn_csr);

    node_kernel<<<(NN + 31) / 32, 512, 0, stream>>>(base, tgt_csr, attn_csr, Vh,
                                                    Wfcb, inQ, gamma, beta, y);
}